// Round 13
// baseline (212.645 us; speedup 1.0000x reference)
//
#include <hip/hip_runtime.h>
#include <math.h>

#define B_   4
#define N_   4096
#define C_   256
#define NH   8      // heads
#define D_   32     // head dim
#define PL_  256    // pooled length
#define IMG  64     // H = W = 64

typedef __attribute__((ext_vector_type(8))) short short8b;
typedef __attribute__((ext_vector_type(4))) float f32x4;
typedef unsigned short ushort_t;

__device__ __forceinline__ ushort_t f2bf(float f) {
    unsigned u = __float_as_uint(f);
    u += 0x7FFFu + ((u >> 16) & 1u);   // RTNE
    return (ushort_t)(u >> 16);
}
__device__ __forceinline__ float bf2f(ushort_t s) {
    return __uint_as_float(((unsigned)s) << 16);
}
__device__ __forceinline__ unsigned pk2(float lo, float hi) {
    return (unsigned)f2bf(lo) | ((unsigned)f2bf(hi) << 16);
}
__device__ __forceinline__ float gelu_f(float v) {
    return 0.5f * v * (1.0f + erff(v * 0.70710678118654752440f));
}

// ---------------------------------------------------------------------------
// prep_all (validated round 9): x->bf16 + weight transposes + CPB MLP.
// ---------------------------------------------------------------------------
__global__ __launch_bounds__(256) void prep_all(const float* __restrict__ x,
                                                const float* __restrict__ q_w,
                                                const float* __restrict__ kv_w,
                                                const float* __restrict__ sr_w,
                                                const float* __restrict__ p_w,
                                                const float* __restrict__ rct,
                                                const float* __restrict__ c1w,
                                                const float* __restrict__ c1b,
                                                const float* __restrict__ c2w,
                                                const float* __restrict__ c2b,
                                                ushort_t* __restrict__ x_bf,
                                                ushort_t* __restrict__ WTall,
                                                ushort_t* __restrict__ pwT,
                                                float* __restrict__ tT)
{
    const int blk = blockIdx.x;
    const int tid = threadIdx.x;
    if (blk < 2048) {
        int gid = blk * 256 + tid;
        const float4* p = (const float4*)(x + (size_t)gid * 8);
        float4 v0 = p[0], v1 = p[1];
        short8b o;
        o[0]=(short)f2bf(v0.x); o[1]=(short)f2bf(v0.y);
        o[2]=(short)f2bf(v0.z); o[3]=(short)f2bf(v0.w);
        o[4]=(short)f2bf(v1.x); o[5]=(short)f2bf(v1.y);
        o[6]=(short)f2bf(v1.z); o[7]=(short)f2bf(v1.w);
        *(short8b*)&x_bf[(size_t)gid * 8] = o;
    } else if (blk < 2208) {
        int wt = (blk - 2048) * 256 + tid;   // 0..40959
        int row = wt >> 5;                   // 0..1279
        int k0  = (wt & 31) << 3;
        const float* W; int N, n; ushort_t* dst;
        if (row < 256)       { W = q_w;  N = 256; n = row;        dst = WTall + (size_t)row * 256; }
        else if (row < 768)  { W = kv_w; N = 512; n = row - 256;  dst = WTall + (size_t)row * 256; }
        else if (row < 1024) { W = sr_w; N = 256; n = row - 768;  dst = WTall + (size_t)row * 256; }
        else                 { W = p_w;  N = 256; n = row - 1024; dst = pwT + (size_t)(row-1024) * 256; }
        short8b v;
        #pragma unroll
        for (int j = 0; j < 8; ++j) v[j] = (short)f2bf(W[(size_t)(k0 + j) * N + n]);
        *(short8b*)&dst[k0] = v;
    } else {
        int l = (blk - 2208) * 4 + (tid >> 6);
        int lane = tid & 63;
        float c0 = rct[l*2+0], c1 = rct[l*2+1];
        float acc[8] = {0,0,0,0,0,0,0,0};
        for (int j = lane; j < 512; j += 64) {
            float hv = fmaxf(c0 * c1w[j] + c1 * c1w[512+j] + c1b[j], 0.f);
            #pragma unroll
            for (int hh = 0; hh < 8; ++hh) acc[hh] += hv * c2w[j*8 + hh];
        }
        #pragma unroll
        for (int o = 32; o > 0; o >>= 1)
            #pragma unroll
            for (int hh = 0; hh < 8; ++hh) acc[hh] += __shfl_xor(acc[hh], o, 64);
        if (lane < 8) tT[lane * 1024 + l] = acc[lane] + c2b[lane];
    }
}

// ---------------------------------------------------------------------------
// gemm_fused v5: 1D grid 10240. id%5==0 -> GEMM block id/5 (2048 blocks,
// in-register norm epilogue, validated r11); else -> pb-gather block
// id - id/5 - 1 (8192 blocks). Interleaving puts memory-bound pb waves
// alongside MFMA waves on every CU (m114 overlap).
// ---------------------------------------------------------------------------
__global__ __launch_bounds__(256) void gemm_fused(const ushort_t* __restrict__ Abf,
                                                  const ushort_t* __restrict__ WTall,
                                                  const float* __restrict__ q_b,
                                                  const float* __restrict__ kv_b,
                                                  const float* __restrict__ sr_b,
                                                  const float* __restrict__ temp,
                                                  const float* __restrict__ qe,
                                                  const int* __restrict__ rpi,
                                                  const float* __restrict__ tT,
                                                  ushort_t* __restrict__ pbl,
                                                  ushort_t* __restrict__ qs_bf,
                                                  ushort_t* __restrict__ knv_bf,
                                                  float* __restrict__ buf_sr)
{
    __shared__ __align__(16) ushort_t Bs[64 * 256];   // 32 KB

    const int id  = blockIdx.x;
    const int tid = threadIdx.x;
    const int g5  = id / 5;

    if (id - g5 * 5 != 0) {      // ---- pb gather ----
        int pbid = id - g5 - 1;                        // 0..8191 bijective
        int gid = pbid * 256 + tid;
        int la   = gid & 15;
        int lg   = (gid >> 4) & 3;
        int t    = (gid >> 6) & 15;
        int wv   = (gid >> 10) & 3;
        int tile = (gid >> 12) & 63;
        int h    = gid >> 18;
        int n  = tile * 64 + wv * 16 + la;
        int p0 = t * 16 + lg * 4;
        int4 r = *(const int4*)&rpi[(size_t)n * PL_ + p0];
        const float* tTh = tT + h * 1024;
        ushort4 o;
        o.x = f2bf(tTh[r.x]);
        o.y = f2bf(tTh[r.y]);
        o.z = f2bf(tTh[r.z]);
        o.w = f2bf(tTh[r.w]);
        *(ushort4*)&pbl[(size_t)gid * 4] = o;
        return;
    }

    const int wv   = tid >> 6;
    const int lane = tid & 63;
    const int la   = lane & 15, lg = lane >> 4;
    const int bx   = g5 & 15;
    const int m0   = (g5 >> 4) * 128 + wv * 32;
    const int n0   = bx * 64;

    {
        const int srow = tid >> 2, sm = tid & 3;
        const ushort_t* wrow = WTall + (size_t)(n0 + srow) * 256;
        #pragma unroll
        for (int c8 = 0; c8 < 8; ++c8) {
            int ck = c8 * 4 + sm;
            short8b v = *(const short8b*)&wrow[ck * 8];
            *(short8b*)&Bs[srow * 256 + ((ck ^ (srow & 3)) * 8)] = v;
        }
    }
    __syncthreads();

    const ushort_t* a0p = Abf + (size_t)(m0 + la) * 256 + lg * 8;
    const ushort_t* a1p = a0p + (size_t)16 * 256;

    f32x4 acc[2][4];
    #pragma unroll
    for (int i = 0; i < 2; ++i)
        #pragma unroll
        for (int j = 0; j < 4; ++j) acc[i][j] = (f32x4){0.f, 0.f, 0.f, 0.f};

    #pragma unroll
    for (int kit = 0; kit < 8; ++kit) {
        short8b a0 = *(const short8b*)(a0p + kit * 32);
        short8b a1 = *(const short8b*)(a1p + kit * 32);
        #pragma unroll
        for (int nf = 0; nf < 4; ++nf) {
            int brow = nf * 16 + la;
            short8b bb = *(const short8b*)&Bs[brow * 256 + (((kit*4 + lg) ^ (la & 3)) * 8)];
            acc[0][nf] = __builtin_amdgcn_mfma_f32_16x16x32_bf16(a0, bb, acc[0][nf], 0, 0, 0);
            acc[1][nf] = __builtin_amdgcn_mfma_f32_16x16x32_bf16(a1, bb, acc[1][nf], 0, 0, 0);
        }
    }

    if (bx < 8) {
        const float* bias = (bx < 4) ? q_b : kv_b;
        const int cb = (bx < 4) ? n0 : (n0 - 256);
        float bv[4];
        #pragma unroll
        for (int nf = 0; nf < 4; ++nf) bv[nf] = bias[cb + nf*16 + la];
        float sp0 = 0.f, sp1 = 0.f;
        if (bx < 4) {
            sp0 = log1pf(expf(temp[bx*2 + 0]));
            sp1 = log1pf(expf(temp[bx*2 + 1]));
        }
        #pragma unroll
        for (int mf = 0; mf < 2; ++mf)
            #pragma unroll
            for (int reg = 0; reg < 4; ++reg) {
                int m = m0 + mf*16 + lg*4 + reg;
                #pragma unroll
                for (int h2 = 0; h2 < 2; ++h2) {
                    float v0 = acc[mf][2*h2][reg]   + bv[2*h2];
                    float v1 = acc[mf][2*h2+1][reg] + bv[2*h2+1];
                    float ss = v0*v0 + v1*v1;
                    ss += __shfl_xor(ss, 1, 64);
                    ss += __shfl_xor(ss, 2, 64);
                    ss += __shfl_xor(ss, 4, 64);
                    ss += __shfl_xor(ss, 8, 64);
                    float inv = rsqrtf(ss + 1e-12f);
                    if (bx < 4) {
                        int head = bx*2 + h2;
                        int n = m & (N_-1);
                        int y = n >> 6, xc = n & 63;
                        int cnt = (1 + (y > 0) + (y < IMG-1)) * (1 + (xc > 0) + (xc < IMG-1));
                        float lc = (cnt == 4) ? 5.5606816f : (cnt == 6) ? 5.5683445f : 5.5797298f;
                        float s2 = (h2 ? sp1 : sp0) * lc;
                        ushort_t* dst = qs_bf + (size_t)m * 256 + head*32;
                        dst[la]      = f2bf((v0*inv + qe[head*32 + la])      * s2);
                        dst[16 + la] = f2bf((v1*inv + qe[head*32 + 16 + la]) * s2);
                    } else {
                        int head = (bx-4)*2 + h2;
                        ushort_t* dst = knv_bf + (size_t)m * 512 + head*32;
                        dst[la]      = f2bf(v0*inv);
                        dst[16 + la] = f2bf(v1*inv);
                    }
                }
            }
    } else if (bx < 12) {
        #pragma unroll
        for (int mf = 0; mf < 2; ++mf)
            #pragma unroll
            for (int nf = 0; nf < 4; ++nf)
                #pragma unroll
                for (int reg = 0; reg < 4; ++reg) {
                    int m = m0 + mf*16 + lg*4 + reg;
                    int col_kv = n0 - 256 + nf*16 + la;
                    knv_bf[(size_t)m * 512 + col_kv] =
                        f2bf(acc[mf][nf][reg] + kv_b[col_kv]);
                }
    } else {
        #pragma unroll
        for (int mf = 0; mf < 2; ++mf)
            #pragma unroll
            for (int nf = 0; nf < 4; ++nf)
                #pragma unroll
                for (int reg = 0; reg < 4; ++reg) {
                    int m = m0 + mf*16 + lg*4 + reg;
                    int c = n0 + nf*16 + la - 768;
                    buf_sr[(size_t)m * 256 + c] = gelu_f(acc[mf][nf][reg] + sr_b[c]);
                }
    }
}

// ---------------------------------------------------------------------------
// gemm_kvp (validated round 11): pooled-kv GEMM with fused norm/transpose.
// ---------------------------------------------------------------------------
__global__ __launch_bounds__(256) void gemm_kvp(const ushort_t* __restrict__ Abf,
                                                const ushort_t* __restrict__ WT,
                                                const float* __restrict__ kv_b,
                                                ushort_t* __restrict__ kp_bf,
                                                ushort_t* __restrict__ vpT_bf)
{
    __shared__ __align__(16) ushort_t Bs[64 * 256];

    const int tid  = threadIdx.x;
    const int wv   = tid >> 6;
    const int lane = tid & 63;
    const int la   = lane & 15, lg = lane >> 4;
    const int m0   = blockIdx.y * 128 + wv * 32;
    const int bx   = blockIdx.x;
    const int n0   = bx * 64;

    {
        const int srow = tid >> 2, sm = tid & 3;
        const ushort_t* wrow = WT + (size_t)(n0 + srow) * 256;
        #pragma unroll
        for (int c8 = 0; c8 < 8; ++c8) {
            int ck = c8 * 4 + sm;
            short8b v = *(const short8b*)&wrow[ck * 8];
            *(short8b*)&Bs[srow * 256 + ((ck ^ (srow & 3)) * 8)] = v;
        }
    }
    __syncthreads();

    const ushort_t* a0p = Abf + (size_t)(m0 + la) * 256 + lg * 8;
    const ushort_t* a1p = a0p + (size_t)16 * 256;

    f32x4 acc[2][4];
    #pragma unroll
    for (int i = 0; i < 2; ++i)
        #pragma unroll
        for (int j = 0; j < 4; ++j) acc[i][j] = (f32x4){0.f, 0.f, 0.f, 0.f};

    #pragma unroll
    for (int kit = 0; kit < 8; ++kit) {
        short8b a0 = *(const short8b*)(a0p + kit * 32);
        short8b a1 = *(const short8b*)(a1p + kit * 32);
        #pragma unroll
        for (int nf = 0; nf < 4; ++nf) {
            int brow = nf * 16 + la;
            short8b bb = *(const short8b*)&Bs[brow * 256 + (((kit*4 + lg) ^ (la & 3)) * 8)];
            acc[0][nf] = __builtin_amdgcn_mfma_f32_16x16x32_bf16(a0, bb, acc[0][nf], 0, 0, 0);
            acc[1][nf] = __builtin_amdgcn_mfma_f32_16x16x32_bf16(a1, bb, acc[1][nf], 0, 0, 0);
        }
    }

    if (bx < 4) {
        float bv[4];
        #pragma unroll
        for (int nf = 0; nf < 4; ++nf) bv[nf] = kv_b[n0 + nf*16 + la];
        #pragma unroll
        for (int mf = 0; mf < 2; ++mf)
            #pragma unroll
            for (int reg = 0; reg < 4; ++reg) {
                int m = m0 + mf*16 + lg*4 + reg;
                int b = m >> 8, p = m & 255;
                #pragma unroll
                for (int h2 = 0; h2 < 2; ++h2) {
                    float v0 = acc[mf][2*h2][reg]   + bv[2*h2];
                    float v1 = acc[mf][2*h2+1][reg] + bv[2*h2+1];
                    float ss = v0*v0 + v1*v1;
                    ss += __shfl_xor(ss, 1, 64);
                    ss += __shfl_xor(ss, 2, 64);
                    ss += __shfl_xor(ss, 4, 64);
                    ss += __shfl_xor(ss, 8, 64);
                    float inv = rsqrtf(ss + 1e-12f);
                    int head = bx*2 + h2;
                    ushort_t* dst = kp_bf + (((size_t)(b*NH + head)) * PL_ + p) * 32;
                    dst[la]      = f2bf(v0*inv);
                    dst[16 + la] = f2bf(v1*inv);
                }
            }
    } else {
        #pragma unroll
        for (int mf = 0; mf < 2; ++mf)
            #pragma unroll
            for (int nf = 0; nf < 4; ++nf)
                #pragma unroll
                for (int reg = 0; reg < 4; ++reg) {
                    int m = m0 + mf*16 + lg*4 + reg;
                    int b = m >> 8, p = m & 255;
                    int col_kv = n0 + nf*16 + la;       // [256,512)
                    int cv = col_kv - 256;
                    int head = cv >> 5, d = cv & 31;
                    vpT_bf[(((size_t)(b*NH + head)) * 32 + d) * 256 + p] =
                        f2bf(acc[mf][nf][reg] + kv_b[col_kv]);
                }
    }
}

// ---------------------------------------------------------------------------
// Generic bf16 MFMA GEMM, K=256 (validated): proj.
// ---------------------------------------------------------------------------
template<int ACT>
__global__ __launch_bounds__(256) void gemm_mfma(const ushort_t* __restrict__ Abf,
                                                 const ushort_t* __restrict__ WT,
                                                 const float* __restrict__ bias,
                                                 float* __restrict__ out,
                                                 int M, int N)
{
    __shared__ __align__(16) ushort_t Bs[64 * 256];

    const int tid  = threadIdx.x;
    const int wv   = tid >> 6;
    const int lane = tid & 63;
    const int la   = lane & 15, lg = lane >> 4;
    const int m0   = blockIdx.y * 128 + wv * 32;
    const int n0   = blockIdx.x * 64;

    {
        const int srow = tid >> 2, sm = tid & 3;
        const ushort_t* wrow = WT + (size_t)(n0 + srow) * 256;
        #pragma unroll
        for (int c8 = 0; c8 < 8; ++c8) {
            int ck = c8 * 4 + sm;
            short8b v = *(const short8b*)&wrow[ck * 8];
            *(short8b*)&Bs[srow * 256 + ((ck ^ (srow & 3)) * 8)] = v;
        }
    }
    __syncthreads();

    const ushort_t* a0p = Abf + (size_t)(m0 + la) * 256 + lg * 8;
    const ushort_t* a1p = a0p + (size_t)16 * 256;

    f32x4 acc[2][4];
    #pragma unroll
    for (int i = 0; i < 2; ++i)
        #pragma unroll
        for (int j = 0; j < 4; ++j) acc[i][j] = (f32x4){0.f, 0.f, 0.f, 0.f};

    #pragma unroll
    for (int kit = 0; kit < 8; ++kit) {
        short8b a0 = *(const short8b*)(a0p + kit * 32);
        short8b a1 = *(const short8b*)(a1p + kit * 32);
        #pragma unroll
        for (int nf = 0; nf < 4; ++nf) {
            int brow = nf * 16 + la;
            short8b bb = *(const short8b*)&Bs[brow * 256 + (((kit*4 + lg) ^ (la & 3)) * 8)];
            acc[0][nf] = __builtin_amdgcn_mfma_f32_16x16x32_bf16(a0, bb, acc[0][nf], 0, 0, 0);
            acc[1][nf] = __builtin_amdgcn_mfma_f32_16x16x32_bf16(a1, bb, acc[1][nf], 0, 0, 0);
        }
    }
    #pragma unroll
    for (int mf = 0; mf < 2; ++mf)
        #pragma unroll
        for (int nf = 0; nf < 4; ++nf)
            #pragma unroll
            for (int reg = 0; reg < 4; ++reg) {
                int m  = m0 + mf * 16 + lg * 4 + reg;
                int nn = n0 + nf * 16 + la;
                float v = acc[mf][nf][reg] + bias[nn];
                if (ACT == 1) v = gelu_f(v);
                out[(size_t)m * N + nn] = v;
            }
}

// ---------------------------------------------------------------------------
// mid_prep v2 (validated round 12): pool_ln (0..1023) + vtrans (1024..1535).
// ---------------------------------------------------------------------------
__global__ __launch_bounds__(256) void mid_prep(const ushort_t* __restrict__ knv,
                                                const float* __restrict__ sr,
                                                const float* __restrict__ g,
                                                const float* __restrict__ bb,
                                                ushort_t* __restrict__ xs,
                                                ushort_t* __restrict__ vT)
{
    __shared__ float red[256];
    __shared__ __align__(16) ushort_t ts[256][40];
    const int blk = blockIdx.x;
    const int tid = threadIdx.x;

    if (blk < 1024) {            // ---- pool_ln ----
        int bp = blk;
        int b = bp >> 8, p = bp & 255;
        int i0 = p >> 4, j0 = p & 15;
        int c = tid;
        float s = 0.f;
        #pragma unroll
        for (int di = 0; di < 4; ++di)
            #pragma unroll
            for (int dj = 0; dj < 4; ++dj) {
                int n = (i0*4 + di) * IMG + (j0*4 + dj);
                s += sr[((size_t)b * N_ + n) * C_ + c];
            }
        s *= (1.f / 16.f);
        red[c] = s; __syncthreads();
        for (int o = 128; o > 0; o >>= 1) { if (c < o) red[c] += red[c+o]; __syncthreads(); }
        float mean = red[0] * (1.f/256.f);
        __syncthreads();
        float dcen = s - mean;
        red[c] = dcen * dcen; __syncthreads();
        for (int o = 128; o > 0; o >>= 1) { if (c < o) red[c] += red[c+o]; __syncthreads(); }
        float var = red[0] * (1.f/256.f);
        float outv = dcen * rsqrtf(var + 1e-5f) * g[c] + bb[c];
        xs[(size_t)bp * C_ + c] = f2bf(outv);
    } else {                     // ---- vtrans ----
        int vb = blk - 1024;
        int nt = vb & 15, bh = vb >> 4;
        const ushort_t* src = knv + ((size_t)((bh >> 3)*N_ + nt*256 + tid)) * 512 + 256 + (bh & 7)*32;
        #pragma unroll
        for (int c = 0; c < 4; ++c)
            *(short8b*)&ts[tid][c*8] = *(const short8b*)&src[c*8];
        __syncthreads();
        int d = tid >> 3, cc = tid & 7;
        ushort_t* dst = vT + ((size_t)bh*32 + d) * (size_t)N_ + nt*256;
        #pragma unroll
        for (int k = 0; k < 4; ++k) {
            int n0 = cc*32 + k*8;
            short8b v;
            #pragma unroll
            for (int j = 0; j < 8; ++j) v[j] = ts[n0+j][d];
            *(short8b*)&dst[n0] = v;
        }
    }
}

// ---------------------------------------------------------------------------
// attn_v6: validated round-8 body, now 2 tiles per block (pairing amortizes
// constant staging + halves per-block launch latency; adjacent tiles share
// vT/knv windows in L2). invs2 computed inline (same log constants as the
// validated r11 epilogue). 1024 blocks, XCD-swizzled.
// ---------------------------------------------------------------------------
__global__ __launch_bounds__(256, 5) void attn_v6(
    const ushort_t* __restrict__ qs_g,   // [B*N,256] bf16 scaled q
    const ushort_t* __restrict__ knv_g,  // [B*N,512] bf16 kn | v
    const ushort_t* __restrict__ kp_g,   // [B][8][256][32] bf16
    const ushort_t* __restrict__ vpT_g,  // [B][8][32][256] bf16
    const ushort_t* __restrict__ vT_g,   // [B][8][32][4096] bf16
    const ushort_t* __restrict__ pbl,    // pool bias, C-frag order
    const float* __restrict__ rpb,       // [8,9]
    const float* __restrict__ qe,        // [8,32]
    const float* __restrict__ temp,      // [8]
    const float* __restrict__ lt,        // [8,32,9]
    const float* __restrict__ lb,        // [8,9]
    ushort_t* __restrict__ outp)         // bf16 [B*N,256]
{
    __shared__ __align__(16) ushort_t qs_lds[64*32];       // 4 KB
    __shared__ __align__(16) ushort_t ltT_lds[16*32];      // 1 KB
    __shared__ __align__(16) ushort_t Wb_lds[4*3*16*40];   // 15 KB
    __shared__ float wloc[64*10];
    __shared__ float wext[64*10];
    __shared__ float rpb_lds[9], elb_lds[9];

    // XCD-aware bijective swizzle over 1024 blocks (8 XCDs x 128)
    const int lin   = blockIdx.x;
    const int virt  = (lin & 7) * 128 + (lin >> 3);
    const int pairi = virt & 31;         // tile pair index (tiles 2p, 2p+1)
    const int hh    = (virt >> 5) & 7;
    const int b     = virt >> 8;

    const int tid  = threadIdx.x;
    const int wv   = tid >> 6;
    const int lane = tid & 63;
    const int la   = lane & 15;
    const int lg   = lane >> 4;
    const int r0   = wv * 16;

    // ---------------- constant staging (once per block) ----------------
    {   // ltT[16][32] bf16 (rows l, cols d); rows >=9 zero
        int l = tid >> 4, dd = (tid & 15) * 2;
        ushort_t a = (l < 9) ? f2bf(lt[hh*288 + dd*9 + l]) : (ushort_t)0;
        ushort_t c = (l < 9) ? f2bf(lt[hh*288 + (dd+1)*9 + l]) : (ushort_t)0;
        ltT_lds[l*32 + dd]   = a;
        ltT_lds[l*32 + dd+1] = c;
    }
    {   // zero Wb band matrix (only band cols are ever rewritten per tile)
        short8b z = {0,0,0,0,0,0,0,0};
        for (int i = tid; i < 960; i += 256) *(short8b*)&Wb_lds[i*8] = z;
    }
    if (tid < 9) {
        int l = tid;
        float e = 0.f;
        for (int d = 0; d < 32; ++d) e += qe[hh*32 + d] * lt[hh*288 + d*9 + l];
        elb_lds[l] = lb[hh*9 + l] - e;
        rpb_lds[l] = rpb[hh*9 + l];
    }
    const float sp = log1pf(expf(temp[hh]));
    const ushort_t* kph = kp_g + ((size_t)(b*NH + hh) * PL_) * 32;
    const ushort_t* vph = vpT_g + ((size_t)(b*NH + hh) * 32) * 256;
    const ushort_t* vTh = vT_g + (size_t)(b*NH + hh) * 32 * N_;

    #pragma unroll 1
    for (int ti = 0; ti < 2; ++ti) {
        const int tile = pairi * 2 + ti;
        if (ti) __syncthreads();   // all waves done reading qs_lds of prev tile

        // ---- stage qs for this tile ----
        {
            int row = tid >> 2, ck = tid & 3;
            short8b v = *(const short8b*)&qs_g[((size_t)(b*N_ + tile*64 + row)) * 256 + hh*32 + ck*8];
            *(short8b*)&qs_lds[row*32 + ((ck ^ (row & 3)) * 8)] = v;
        }
        __syncthreads();

        const short8b af = *(const short8b*)&qs_lds[(r0+la)*32 + ((lg ^ (la & 3)) * 8)];

        // ---- local QK: Gram-band MFMA ----
        {
            f32x4 G[3][2];
            const f32x4 zc = {0.f,0.f,0.f,0.f};
            #pragma unroll
            for (int dyi = 0; dyi < 3; ++dyi) {
                int cy = tile + dyi - 1;
                cy = cy < 0 ? 0 : (cy > 63 ? 63 : cy);
                #pragma unroll
                for (int f = 0; f < 2; ++f) {
                    int xp = wv*16 - 8 + 16*f + la;
                    xp = xp < 0 ? 0 : (xp > 63 ? 63 : xp);
                    const short8b kf = *(const short8b*)
                        &knv_g[((size_t)(b*N_ + cy*64 + xp)) * 512 + hh*32 + lg*8];
                    G[dyi][f] = __builtin_amdgcn_mfma_f32_16x16x32_bf16(af, kf, zc, 0, 0, 0);
                }
            }
            #pragma unroll
            for (int f = 0; f < 2; ++f)
                #pragma unroll
                for (int reg = 0; reg < 4; ++reg) {
                    int r  = lg*4 + reg;
                    int dx = la + 16*f - 8 - r;
                    if (dx >= -1 && dx <= 1) {
                        #pragma unroll
                        for (int dyi = 0; dyi < 3; ++dyi)
                            wloc[(r0 + r)*10 + dyi*3 + dx + 1] = G[dyi][f][reg];
                    }
                }
        }

        // ---- extras MFMA: s3 = qs . lt (invs2 inline) ----
        {
            const short8b ltf = *(const short8b*)&ltT_lds[la*32 + lg*8];
            const f32x4 zc = {0.f,0.f,0.f,0.f};
            f32x4 E = __builtin_amdgcn_mfma_f32_16x16x32_bf16(af, ltf, zc, 0, 0, 0);
            if (la < 9) {
                int ci = 1 + (tile > 0) + (tile < IMG-1);
                #pragma unroll
                for (int reg = 0; reg < 4; ++reg) {
                    int rr = r0 + lg*4 + reg;
                    int cj = 1 + (rr > 0) + (rr < IMG-1);
                    int cnt = ci * cj;
                    float lc = (cnt == 4) ? 5.5606816f : (cnt == 6) ? 5.5683445f : 5.5797298f;
                    float is2 = 1.0f / (sp * lc);
                    wext[rr*10 + la] = is2 * E[reg] + elb_lds[la];
                }
            }
        }

        // ---- pool QK^T ----
        const ushort_t* pbw = pbl + ((((size_t)hh * 64 + tile) * 4 + wv) * 4096);

        f32x4 acc[16];
        #pragma unroll
        for (int t = 0; t < 16; ++t) {
            ushort4 b4 = *(const ushort4*)&pbw[t*256 + lg*64 + la*4];
            f32x4 c;
            c[0] = bf2f(b4.x); c[1] = bf2f(b4.y); c[2] = bf2f(b4.z); c[3] = bf2f(b4.w);
            short8b kf = *(const short8b*)&kph[(t*16 + la)*32 + lg*8];
            acc[t] = __builtin_amdgcn_mfma_f32_16x16x32_bf16(kf, af, c, 0, 0, 0);
        }

        // ---- joint softmax ----
        const int rr = r0 + la;
        float mx = -3.0e38f;
        #pragma unroll
        for (int t = 0; t < 16; ++t)
            #pragma unroll
            for (int reg = 0; reg < 4; ++reg) mx = fmaxf(mx, acc[t][reg]);
        mx = fmaxf(mx, __shfl_xor(mx, 16, 64));
        mx = fmaxf(mx, __shfl_xor(mx, 32, 64));
        float lv[9];
        #pragma unroll
        for (int l = 0; l < 9; ++l) {
            int dy = l/3 - 1, dx = l%3 - 1;
            int yy = tile + dy, xx = rr + dx;
            bool val = (yy >= 0 && yy < IMG && xx >= 0 && xx < IMG);
            lv[l] = val ? (wloc[rr*10 + l] + rpb_lds[l]) : -1e9f;
            mx = fmaxf(mx, lv[l]);
        }

        float s = 0.f;
        #pragma unroll
        for (int t = 0; t < 16; ++t)
            #pragma unroll
            for (int reg = 0; reg < 4; ++reg) {
                float e = __expf(acc[t][reg] - mx);
                acc[t][reg] = e;
                s += e;
            }
        s += __shfl_xor(s, 16, 64);
        s += __shfl_xor(s, 32, 64);
        float sl = 0.f;
        float el[9];
        #pragma unroll
        for (int l = 0; l < 9; ++l) { el[l] = __expf(lv[l] - mx); sl += el[l]; }
        s += sl;
        const float inv = 1.f / s;

        if (lg == 0) {
            #pragma unroll
            for (int l = 0; l < 9; ++l) {
                int dy = l/3 - 1, dx = l%3 - 1;
                int yy = tile + dy, xx = rr + dx;
                bool val = (yy >= 0 && yy < IMG && xx >= 0 && xx < IMG);
                float wl = el[l]*inv + wext[rr*10 + l];
                Wb_lds[((wv*3 + l/3)*16 + la)*40 + (la + 8 + dx)] =
                    val ? f2bf(wl) : (ushort_t)0;
            }
        }

        // ---- PV ----
        f32x4 o0 = {0.f,0.f,0.f,0.f}, o1 = {0.f,0.f,0.f,0.f};

        {   // local: per dy, A=Wb[wv][dy], B=vT window
            #pragma unroll
            for (int dyi = 0; dyi < 3; ++dyi) {
                int cy = tile + dyi - 1;
                cy = cy < 0 ? 0 : (cy > 63 ? 63 : cy);
                int nb = cy*64 + wv*16 - 8 + lg*8;
                nb = nb < 0 ? 0 : (nb > (N_ - 8) ? (N_ - 8) : nb);
                short8b wf = *(const short8b*)&Wb_lds[((wv*3 + dyi)*16 + la)*40 + lg*8];
                short8b vf0 = *(const short8b*)&vTh[(size_t)la * N_ + nb];
                short8b vf1 = *(const short8b*)&vTh[(size_t)(16 + la) * N_ + nb];
                o0 = __builtin_amdgcn_mfma_f32_16x16x32_bf16(wf, vf0, o0, 0, 0, 0);
                o1 = __builtin_amdgcn_mfma_f32_16x16x32_bf16(wf, vf1, o1, 0, 0, 0);
            }
        }

        {   // pool PV: shuffle-permuted A-frags
            const int src0 = la + 32*(lg & 1);
            const int src1 = src0 + 16;
            const bool hi  = (lg >= 2);
            #pragma unroll
            for (int kk = 0; kk < 8; ++kk) {
                unsigned A0 = pk2(acc[2*kk][0]*inv,   acc[2*kk][1]*inv);
                unsigned A1 = pk2(acc[2*kk][2]*inv,   acc[2*kk][3]*inv);
                unsigned B0 = pk2(acc[2*kk+1][0]*inv, acc[2*kk+1][1]*inv);
                unsigned B1 = pk2(acc[2*kk+1][2]*inv, acc[2*kk+1][3]*inv);
                unsigned xa0 = __shfl(A0, src0, 64), xb0 = __shfl(B0, src0, 64);
                unsigned xa1 = __shfl(A1, src0, 64), xb1 = __shfl(B1, src0, 64);
                unsigned ya0 = __shfl(A0, src1, 64), yb0 = __shfl(B0, src1, 64);
                unsigned ya1 = __shfl(A1, src1, 64), yb1 = __shfl(B1, src1, 64);
                union { unsigned u[4]; short8b v; } wf;
                wf.u[0] = hi ? xb0 : xa0;
                wf.u[1] = hi ? xb1 : xa1;
                wf.u[2] = hi ? yb0 : ya0;
                wf.u[3] = hi ? yb1 : ya1;
                short8b vf0 = *(const short8b*)&vph[(size_t)la*256      + kk*32 + lg*8];
                short8b vf1 = *(const short8b*)&vph[(size_t)(16+la)*256 + kk*32 + lg*8];
                o0 = __builtin_amdgcn_mfma_f32_16x16x32_bf16(wf.v, vf0, o0, 0, 0, 0);
                o1 = __builtin_amdgcn_mfma_f32_16x16x32_bf16(wf.v, vf1, o1, 0, 0, 0);
            }
        }

        #pragma unroll
        for (int reg = 0; reg < 4; ++reg) {
            int r2 = r0 + lg*4 + reg;
            int n  = tile*64 + r2;
            ushort_t* orow = outp + ((size_t)(b*N_ + n)) * C_ + hh*32;
            orow[la]      = f2bf(o0[reg]);
            orow[16 + la] = f2bf(o1[reg]);
        }
    }
}

// ---------------------------------------------------------------------------
extern "C" void kernel_launch(void* const* d_in, const int* in_sizes, int n_in,
                              void* d_out, int out_size, void* d_ws, size_t ws_size,
                              hipStream_t stream) {
    const float* x    = (const float*)d_in[0];
    const float* rct  = (const float*)d_in[1];
    const int*   rpi  = (const int*)  d_in[2];
    const float* q_w  = (const float*)d_in[3];
    const float* q_b  = (const float*)d_in[4];
    const float* kv_w = (const float*)d_in[5];
    const float* kv_b = (const float*)d_in[6];
    const float* temp = (const float*)d_in[7];
    const float* qe   = (const float*)d_in[8];
    const float* sr_w = (const float*)d_in[9];
    const float* sr_b = (const float*)d_in[10];
    const float* ng   = (const float*)d_in[11];
    const float* nb   = (const float*)d_in[12];
    const float* c1w  = (const float*)d_in[13];
    const float* c1b  = (const float*)d_in[14];
    const float* c2w  = (const float*)d_in[15];
    const float* c2b  = (const float*)d_in[16];
    const float* rpb  = (const float*)d_in[17];
    const float* lt   = (const float*)d_in[18];
    const float* lb   = (const float*)d_in[19];
    const float* p_w  = (const float*)d_in[20];
    const float* p_b  = (const float*)d_in[21];
    float* out = (float*)d_out;

    float* ws = (float*)d_ws;
    const size_t MN = (size_t)B_ * N_;               // 16384
    float* buf_sr  = ws;                             // [MN,256] f32
    float* buf_t   = buf_sr + MN * 256;              // [8,1024]
    ushort_t* x_bf   = (ushort_t*)(buf_t + 8*1024);  // [MN,256]
    ushort_t* pre_bf = x_bf   + MN * 256;            // [MN,256] attn out
    ushort_t* WTall  = pre_bf + MN * 256;            // [1024,256]
    ushort_t* pwT    = WTall  + 1024*256;            // [256,256]
    ushort_t* qs_bf  = pwT    + 256*256;             // [MN,256]
    ushort_t* knv_bf = qs_bf  + MN * 256;            // [MN,512]
    ushort_t* kp_bf  = knv_bf + MN * 512;            // [B*8*256*32]
    ushort_t* vpT_bf = kp_bf  + (size_t)B_*NH*PL_*32;// [B*8*32*256]
    ushort_t* vT_bf  = vpT_bf + (size_t)B_*NH*32*PL_;// [B*8*32*4096]
    ushort_t* pbl    = vT_bf  + (size_t)B_*NH*32*N_; // [2097152*4]
    ushort_t* xs_bf  = pbl    + (size_t)2097152*4;   // [B*PL,256]

    const int M = (int)MN;  // 16384

    // 1: x convert + weight transposes + CPB MLP
    prep_all<<<2464, 256, 0, stream>>>(x, q_w, kv_w, sr_w, p_w, rct,
                                       c1w, c1b, c2w, c2b, x_bf, WTall, pwT, buf_t);
    // 2: fused q|kv|sr GEMM with pb-gather blocks INTERLEAVED (1D grid)
    gemm_fused<<<10240, 256, 0, stream>>>(x_bf, WTall, q_b, kv_b, sr_b,
                                          temp, qe, rpi, buf_t, pbl,
                                          qs_bf, knv_bf, buf_sr);
    // 3: pool_ln + vtrans
    mid_prep<<<1536, 256, 0, stream>>>(knv_bf, buf_sr, ng, nb, xs_bf, vT_bf);
    // 4: pooled kv GEMM with fused norm/transpose epilogue
    gemm_kvp<<<dim3(8, 8), 256, 0, stream>>>(xs_bf, WTall + 256*256, kv_b,
                                             kp_bf, vpT_bf);
    // 5: attention (2 tiles/block, XCD-swizzled)
    attn_v6<<<1024, 256, 0, stream>>>(qs_bf, knv_bf, kp_bf, vpT_bf, vT_bf,
                                      pbl, rpb, qe, temp, lt, lb, pre_bf);
    // 6: output projection
    gemm_mfma<0><<<dim3(4, M/128), 256, 0, stream>>>(pre_bf, pwT, p_b, out, M, 256);
}

// Round 14
// 135.221 us; speedup vs baseline: 1.5726x; 1.5726x over previous
//
#include <hip/hip_runtime.h>
#include <math.h>

#define B_   4
#define N_   4096
#define C_   256
#define NH   8      // heads
#define D_   32     // head dim
#define PL_  256    // pooled length
#define IMG  64     // H = W = 64

typedef __attribute__((ext_vector_type(8))) short short8b;
typedef __attribute__((ext_vector_type(4))) float f32x4;
typedef unsigned short ushort_t;

__device__ __forceinline__ ushort_t f2bf(float f) {
    unsigned u = __float_as_uint(f);
    u += 0x7FFFu + ((u >> 16) & 1u);   // RTNE
    return (ushort_t)(u >> 16);
}
__device__ __forceinline__ float bf2f(ushort_t s) {
    return __uint_as_float(((unsigned)s) << 16);
}
__device__ __forceinline__ unsigned pk2(float lo, float hi) {
    return (unsigned)f2bf(lo) | ((unsigned)f2bf(hi) << 16);
}
__device__ __forceinline__ float gelu_f(float v) {
    return 0.5f * v * (1.0f + erff(v * 0.70710678118654752440f));
}

// ---------------------------------------------------------------------------
// prep_all (validated round 9): x->bf16 + weight transposes + CPB MLP.
// ---------------------------------------------------------------------------
__global__ __launch_bounds__(256) void prep_all(const float* __restrict__ x,
                                                const float* __restrict__ q_w,
                                                const float* __restrict__ kv_w,
                                                const float* __restrict__ sr_w,
                                                const float* __restrict__ p_w,
                                                const float* __restrict__ rct,
                                                const float* __restrict__ c1w,
                                                const float* __restrict__ c1b,
                                                const float* __restrict__ c2w,
                                                const float* __restrict__ c2b,
                                                ushort_t* __restrict__ x_bf,
                                                ushort_t* __restrict__ WTall,
                                                ushort_t* __restrict__ pwT,
                                                float* __restrict__ tT)
{
    const int blk = blockIdx.x;
    const int tid = threadIdx.x;
    if (blk < 2048) {
        int gid = blk * 256 + tid;
        const float4* p = (const float4*)(x + (size_t)gid * 8);
        float4 v0 = p[0], v1 = p[1];
        short8b o;
        o[0]=(short)f2bf(v0.x); o[1]=(short)f2bf(v0.y);
        o[2]=(short)f2bf(v0.z); o[3]=(short)f2bf(v0.w);
        o[4]=(short)f2bf(v1.x); o[5]=(short)f2bf(v1.y);
        o[6]=(short)f2bf(v1.z); o[7]=(short)f2bf(v1.w);
        *(short8b*)&x_bf[(size_t)gid * 8] = o;
    } else if (blk < 2208) {
        int wt = (blk - 2048) * 256 + tid;   // 0..40959
        int row = wt >> 5;                   // 0..1279
        int k0  = (wt & 31) << 3;
        const float* W; int N, n; ushort_t* dst;
        if (row < 256)       { W = q_w;  N = 256; n = row;        dst = WTall + (size_t)row * 256; }
        else if (row < 768)  { W = kv_w; N = 512; n = row - 256;  dst = WTall + (size_t)row * 256; }
        else if (row < 1024) { W = sr_w; N = 256; n = row - 768;  dst = WTall + (size_t)row * 256; }
        else                 { W = p_w;  N = 256; n = row - 1024; dst = pwT + (size_t)(row-1024) * 256; }
        short8b v;
        #pragma unroll
        for (int j = 0; j < 8; ++j) v[j] = (short)f2bf(W[(size_t)(k0 + j) * N + n]);
        *(short8b*)&dst[k0] = v;
    } else {
        int l = (blk - 2208) * 4 + (tid >> 6);
        int lane = tid & 63;
        float c0 = rct[l*2+0], c1 = rct[l*2+1];
        float acc[8] = {0,0,0,0,0,0,0,0};
        for (int j = lane; j < 512; j += 64) {
            float hv = fmaxf(c0 * c1w[j] + c1 * c1w[512+j] + c1b[j], 0.f);
            #pragma unroll
            for (int hh = 0; hh < 8; ++hh) acc[hh] += hv * c2w[j*8 + hh];
        }
        #pragma unroll
        for (int o = 32; o > 0; o >>= 1)
            #pragma unroll
            for (int hh = 0; hh < 8; ++hh) acc[hh] += __shfl_xor(acc[hh], o, 64);
        if (lane < 8) tT[lane * 1024 + l] = acc[lane] + c2b[lane];
    }
}

// ---------------------------------------------------------------------------
// gemm_fused v5 (validated round 13): 1D grid 10240. id%5==0 -> GEMM block
// id/5; else -> pb-gather block id-id/5-1. Interleaving overlaps memory-bound
// pb waves with MFMA waves (m114) — saved ~10us in r13.
// ---------------------------------------------------------------------------
__global__ __launch_bounds__(256) void gemm_fused(const ushort_t* __restrict__ Abf,
                                                  const ushort_t* __restrict__ WTall,
                                                  const float* __restrict__ q_b,
                                                  const float* __restrict__ kv_b,
                                                  const float* __restrict__ sr_b,
                                                  const float* __restrict__ temp,
                                                  const float* __restrict__ qe,
                                                  const int* __restrict__ rpi,
                                                  const float* __restrict__ tT,
                                                  ushort_t* __restrict__ pbl,
                                                  ushort_t* __restrict__ qs_bf,
                                                  ushort_t* __restrict__ knv_bf,
                                                  float* __restrict__ buf_sr)
{
    __shared__ __align__(16) ushort_t Bs[64 * 256];   // 32 KB

    const int id  = blockIdx.x;
    const int tid = threadIdx.x;
    const int g5  = id / 5;

    if (id - g5 * 5 != 0) {      // ---- pb gather ----
        int pbid = id - g5 - 1;                        // 0..8191 bijective
        int gid = pbid * 256 + tid;
        int la   = gid & 15;
        int lg   = (gid >> 4) & 3;
        int t    = (gid >> 6) & 15;
        int wv   = (gid >> 10) & 3;
        int tile = (gid >> 12) & 63;
        int h    = gid >> 18;
        int n  = tile * 64 + wv * 16 + la;
        int p0 = t * 16 + lg * 4;
        int4 r = *(const int4*)&rpi[(size_t)n * PL_ + p0];
        const float* tTh = tT + h * 1024;
        ushort4 o;
        o.x = f2bf(tTh[r.x]);
        o.y = f2bf(tTh[r.y]);
        o.z = f2bf(tTh[r.z]);
        o.w = f2bf(tTh[r.w]);
        *(ushort4*)&pbl[(size_t)gid * 4] = o;
        return;
    }

    const int wv   = tid >> 6;
    const int lane = tid & 63;
    const int la   = lane & 15, lg = lane >> 4;
    const int bx   = g5 & 15;
    const int m0   = (g5 >> 4) * 128 + wv * 32;
    const int n0   = bx * 64;

    {
        const int srow = tid >> 2, sm = tid & 3;
        const ushort_t* wrow = WTall + (size_t)(n0 + srow) * 256;
        #pragma unroll
        for (int c8 = 0; c8 < 8; ++c8) {
            int ck = c8 * 4 + sm;
            short8b v = *(const short8b*)&wrow[ck * 8];
            *(short8b*)&Bs[srow * 256 + ((ck ^ (srow & 3)) * 8)] = v;
        }
    }
    __syncthreads();

    const ushort_t* a0p = Abf + (size_t)(m0 + la) * 256 + lg * 8;
    const ushort_t* a1p = a0p + (size_t)16 * 256;

    f32x4 acc[2][4];
    #pragma unroll
    for (int i = 0; i < 2; ++i)
        #pragma unroll
        for (int j = 0; j < 4; ++j) acc[i][j] = (f32x4){0.f, 0.f, 0.f, 0.f};

    #pragma unroll
    for (int kit = 0; kit < 8; ++kit) {
        short8b a0 = *(const short8b*)(a0p + kit * 32);
        short8b a1 = *(const short8b*)(a1p + kit * 32);
        #pragma unroll
        for (int nf = 0; nf < 4; ++nf) {
            int brow = nf * 16 + la;
            short8b bb = *(const short8b*)&Bs[brow * 256 + (((kit*4 + lg) ^ (la & 3)) * 8)];
            acc[0][nf] = __builtin_amdgcn_mfma_f32_16x16x32_bf16(a0, bb, acc[0][nf], 0, 0, 0);
            acc[1][nf] = __builtin_amdgcn_mfma_f32_16x16x32_bf16(a1, bb, acc[1][nf], 0, 0, 0);
        }
    }

    if (bx < 8) {
        const float* bias = (bx < 4) ? q_b : kv_b;
        const int cb = (bx < 4) ? n0 : (n0 - 256);
        float bv[4];
        #pragma unroll
        for (int nf = 0; nf < 4; ++nf) bv[nf] = bias[cb + nf*16 + la];
        float sp0 = 0.f, sp1 = 0.f;
        if (bx < 4) {
            sp0 = log1pf(expf(temp[bx*2 + 0]));
            sp1 = log1pf(expf(temp[bx*2 + 1]));
        }
        #pragma unroll
        for (int mf = 0; mf < 2; ++mf)
            #pragma unroll
            for (int reg = 0; reg < 4; ++reg) {
                int m = m0 + mf*16 + lg*4 + reg;
                #pragma unroll
                for (int h2 = 0; h2 < 2; ++h2) {
                    float v0 = acc[mf][2*h2][reg]   + bv[2*h2];
                    float v1 = acc[mf][2*h2+1][reg] + bv[2*h2+1];
                    float ss = v0*v0 + v1*v1;
                    ss += __shfl_xor(ss, 1, 64);
                    ss += __shfl_xor(ss, 2, 64);
                    ss += __shfl_xor(ss, 4, 64);
                    ss += __shfl_xor(ss, 8, 64);
                    float inv = rsqrtf(ss + 1e-12f);
                    if (bx < 4) {
                        int head = bx*2 + h2;
                        int n = m & (N_-1);
                        int y = n >> 6, xc = n & 63;
                        int cnt = (1 + (y > 0) + (y < IMG-1)) * (1 + (xc > 0) + (xc < IMG-1));
                        float lc = (cnt == 4) ? 5.5606816f : (cnt == 6) ? 5.5683445f : 5.5797298f;
                        float s2 = (h2 ? sp1 : sp0) * lc;
                        ushort_t* dst = qs_bf + (size_t)m * 256 + head*32;
                        dst[la]      = f2bf((v0*inv + qe[head*32 + la])      * s2);
                        dst[16 + la] = f2bf((v1*inv + qe[head*32 + 16 + la]) * s2);
                    } else {
                        int head = (bx-4)*2 + h2;
                        ushort_t* dst = knv_bf + (size_t)m * 512 + head*32;
                        dst[la]      = f2bf(v0*inv);
                        dst[16 + la] = f2bf(v1*inv);
                    }
                }
            }
    } else if (bx < 12) {
        #pragma unroll
        for (int mf = 0; mf < 2; ++mf)
            #pragma unroll
            for (int nf = 0; nf < 4; ++nf)
                #pragma unroll
                for (int reg = 0; reg < 4; ++reg) {
                    int m = m0 + mf*16 + lg*4 + reg;
                    int col_kv = n0 - 256 + nf*16 + la;
                    knv_bf[(size_t)m * 512 + col_kv] =
                        f2bf(acc[mf][nf][reg] + kv_b[col_kv]);
                }
    } else {
        #pragma unroll
        for (int mf = 0; mf < 2; ++mf)
            #pragma unroll
            for (int nf = 0; nf < 4; ++nf)
                #pragma unroll
                for (int reg = 0; reg < 4; ++reg) {
                    int m = m0 + mf*16 + lg*4 + reg;
                    int c = n0 + nf*16 + la - 768;
                    buf_sr[(size_t)m * 256 + c] = gelu_f(acc[mf][nf][reg] + sr_b[c]);
                }
    }
}

// ---------------------------------------------------------------------------
// gemm_kvp (validated round 11): pooled-kv GEMM with fused norm/transpose.
// ---------------------------------------------------------------------------
__global__ __launch_bounds__(256) void gemm_kvp(const ushort_t* __restrict__ Abf,
                                                const ushort_t* __restrict__ WT,
                                                const float* __restrict__ kv_b,
                                                ushort_t* __restrict__ kp_bf,
                                                ushort_t* __restrict__ vpT_bf)
{
    __shared__ __align__(16) ushort_t Bs[64 * 256];

    const int tid  = threadIdx.x;
    const int wv   = tid >> 6;
    const int lane = tid & 63;
    const int la   = lane & 15, lg = lane >> 4;
    const int m0   = blockIdx.y * 128 + wv * 32;
    const int bx   = blockIdx.x;
    const int n0   = bx * 64;

    {
        const int srow = tid >> 2, sm = tid & 3;
        const ushort_t* wrow = WT + (size_t)(n0 + srow) * 256;
        #pragma unroll
        for (int c8 = 0; c8 < 8; ++c8) {
            int ck = c8 * 4 + sm;
            short8b v = *(const short8b*)&wrow[ck * 8];
            *(short8b*)&Bs[srow * 256 + ((ck ^ (srow & 3)) * 8)] = v;
        }
    }
    __syncthreads();

    const ushort_t* a0p = Abf + (size_t)(m0 + la) * 256 + lg * 8;
    const ushort_t* a1p = a0p + (size_t)16 * 256;

    f32x4 acc[2][4];
    #pragma unroll
    for (int i = 0; i < 2; ++i)
        #pragma unroll
        for (int j = 0; j < 4; ++j) acc[i][j] = (f32x4){0.f, 0.f, 0.f, 0.f};

    #pragma unroll
    for (int kit = 0; kit < 8; ++kit) {
        short8b a0 = *(const short8b*)(a0p + kit * 32);
        short8b a1 = *(const short8b*)(a1p + kit * 32);
        #pragma unroll
        for (int nf = 0; nf < 4; ++nf) {
            int brow = nf * 16 + la;
            short8b bb = *(const short8b*)&Bs[brow * 256 + (((kit*4 + lg) ^ (la & 3)) * 8)];
            acc[0][nf] = __builtin_amdgcn_mfma_f32_16x16x32_bf16(a0, bb, acc[0][nf], 0, 0, 0);
            acc[1][nf] = __builtin_amdgcn_mfma_f32_16x16x32_bf16(a1, bb, acc[1][nf], 0, 0, 0);
        }
    }

    if (bx < 4) {
        float bv[4];
        #pragma unroll
        for (int nf = 0; nf < 4; ++nf) bv[nf] = kv_b[n0 + nf*16 + la];
        #pragma unroll
        for (int mf = 0; mf < 2; ++mf)
            #pragma unroll
            for (int reg = 0; reg < 4; ++reg) {
                int m = m0 + mf*16 + lg*4 + reg;
                int b = m >> 8, p = m & 255;
                #pragma unroll
                for (int h2 = 0; h2 < 2; ++h2) {
                    float v0 = acc[mf][2*h2][reg]   + bv[2*h2];
                    float v1 = acc[mf][2*h2+1][reg] + bv[2*h2+1];
                    float ss = v0*v0 + v1*v1;
                    ss += __shfl_xor(ss, 1, 64);
                    ss += __shfl_xor(ss, 2, 64);
                    ss += __shfl_xor(ss, 4, 64);
                    ss += __shfl_xor(ss, 8, 64);
                    float inv = rsqrtf(ss + 1e-12f);
                    int head = bx*2 + h2;
                    ushort_t* dst = kp_bf + (((size_t)(b*NH + head)) * PL_ + p) * 32;
                    dst[la]      = f2bf(v0*inv);
                    dst[16 + la] = f2bf(v1*inv);
                }
            }
    } else {
        #pragma unroll
        for (int mf = 0; mf < 2; ++mf)
            #pragma unroll
            for (int nf = 0; nf < 4; ++nf)
                #pragma unroll
                for (int reg = 0; reg < 4; ++reg) {
                    int m = m0 + mf*16 + lg*4 + reg;
                    int b = m >> 8, p = m & 255;
                    int col_kv = n0 + nf*16 + la;       // [256,512)
                    int cv = col_kv - 256;
                    int head = cv >> 5, d = cv & 31;
                    vpT_bf[(((size_t)(b*NH + head)) * 32 + d) * 256 + p] =
                        f2bf(acc[mf][nf][reg] + kv_b[col_kv]);
                }
    }
}

// ---------------------------------------------------------------------------
// Generic bf16 MFMA GEMM, K=256 (validated): proj.
// ---------------------------------------------------------------------------
template<int ACT>
__global__ __launch_bounds__(256) void gemm_mfma(const ushort_t* __restrict__ Abf,
                                                 const ushort_t* __restrict__ WT,
                                                 const float* __restrict__ bias,
                                                 float* __restrict__ out,
                                                 int M, int N)
{
    __shared__ __align__(16) ushort_t Bs[64 * 256];

    const int tid  = threadIdx.x;
    const int wv   = tid >> 6;
    const int lane = tid & 63;
    const int la   = lane & 15, lg = lane >> 4;
    const int m0   = blockIdx.y * 128 + wv * 32;
    const int n0   = blockIdx.x * 64;

    {
        const int srow = tid >> 2, sm = tid & 3;
        const ushort_t* wrow = WT + (size_t)(n0 + srow) * 256;
        #pragma unroll
        for (int c8 = 0; c8 < 8; ++c8) {
            int ck = c8 * 4 + sm;
            short8b v = *(const short8b*)&wrow[ck * 8];
            *(short8b*)&Bs[srow * 256 + ((ck ^ (srow & 3)) * 8)] = v;
        }
    }
    __syncthreads();

    const ushort_t* a0p = Abf + (size_t)(m0 + la) * 256 + lg * 8;
    const ushort_t* a1p = a0p + (size_t)16 * 256;

    f32x4 acc[2][4];
    #pragma unroll
    for (int i = 0; i < 2; ++i)
        #pragma unroll
        for (int j = 0; j < 4; ++j) acc[i][j] = (f32x4){0.f, 0.f, 0.f, 0.f};

    #pragma unroll
    for (int kit = 0; kit < 8; ++kit) {
        short8b a0 = *(const short8b*)(a0p + kit * 32);
        short8b a1 = *(const short8b*)(a1p + kit * 32);
        #pragma unroll
        for (int nf = 0; nf < 4; ++nf) {
            int brow = nf * 16 + la;
            short8b bb = *(const short8b*)&Bs[brow * 256 + (((kit*4 + lg) ^ (la & 3)) * 8)];
            acc[0][nf] = __builtin_amdgcn_mfma_f32_16x16x32_bf16(a0, bb, acc[0][nf], 0, 0, 0);
            acc[1][nf] = __builtin_amdgcn_mfma_f32_16x16x32_bf16(a1, bb, acc[1][nf], 0, 0, 0);
        }
    }
    #pragma unroll
    for (int mf = 0; mf < 2; ++mf)
        #pragma unroll
        for (int nf = 0; nf < 4; ++nf)
            #pragma unroll
            for (int reg = 0; reg < 4; ++reg) {
                int m  = m0 + mf * 16 + lg * 4 + reg;
                int nn = n0 + nf * 16 + la;
                float v = acc[mf][nf][reg] + bias[nn];
                if (ACT == 1) v = gelu_f(v);
                out[(size_t)m * N + nn] = v;
            }
}

// ---------------------------------------------------------------------------
// mid_prep v2 (validated round 12): pool_ln (0..1023) + vtrans (1024..1535).
// ---------------------------------------------------------------------------
__global__ __launch_bounds__(256) void mid_prep(const ushort_t* __restrict__ knv,
                                                const float* __restrict__ sr,
                                                const float* __restrict__ g,
                                                const float* __restrict__ bb,
                                                ushort_t* __restrict__ xs,
                                                ushort_t* __restrict__ vT)
{
    __shared__ float red[256];
    __shared__ __align__(16) ushort_t ts[256][40];
    const int blk = blockIdx.x;
    const int tid = threadIdx.x;

    if (blk < 1024) {            // ---- pool_ln ----
        int bp = blk;
        int b = bp >> 8, p = bp & 255;
        int i0 = p >> 4, j0 = p & 15;
        int c = tid;
        float s = 0.f;
        #pragma unroll
        for (int di = 0; di < 4; ++di)
            #pragma unroll
            for (int dj = 0; dj < 4; ++dj) {
                int n = (i0*4 + di) * IMG + (j0*4 + dj);
                s += sr[((size_t)b * N_ + n) * C_ + c];
            }
        s *= (1.f / 16.f);
        red[c] = s; __syncthreads();
        for (int o = 128; o > 0; o >>= 1) { if (c < o) red[c] += red[c+o]; __syncthreads(); }
        float mean = red[0] * (1.f/256.f);
        __syncthreads();
        float dcen = s - mean;
        red[c] = dcen * dcen; __syncthreads();
        for (int o = 128; o > 0; o >>= 1) { if (c < o) red[c] += red[c+o]; __syncthreads(); }
        float var = red[0] * (1.f/256.f);
        float outv = dcen * rsqrtf(var + 1e-5f) * g[c] + bb[c];
        xs[(size_t)bp * C_ + c] = f2bf(outv);
    } else {                     // ---- vtrans ----
        int vb = blk - 1024;
        int nt = vb & 15, bh = vb >> 4;
        const ushort_t* src = knv + ((size_t)((bh >> 3)*N_ + nt*256 + tid)) * 512 + 256 + (bh & 7)*32;
        #pragma unroll
        for (int c = 0; c < 4; ++c)
            *(short8b*)&ts[tid][c*8] = *(const short8b*)&src[c*8];
        __syncthreads();
        int d = tid >> 3, cc = tid & 7;
        ushort_t* dst = vT + ((size_t)bh*32 + d) * (size_t)N_ + nt*256;
        #pragma unroll
        for (int k = 0; k < 4; ++k) {
            int n0 = cc*32 + k*8;
            short8b v;
            #pragma unroll
            for (int j = 0; j < 8; ++j) v[j] = ts[n0+j][d];
            *(short8b*)&dst[n0] = v;
        }
    }
}

// ---------------------------------------------------------------------------
// attn_v4 (validated rounds 8/10/12, ~53.5 µs): single tile per block, XCD
// swizzle, NO min-waves launch bound (r13's (256,5) spilled acc[16] to
// scratch: VGPR 96->48, WRITE_SIZE 8->185MB, 145us — reverted).
// ---------------------------------------------------------------------------
__global__ __launch_bounds__(256) void attn_v4(
    const ushort_t* __restrict__ qs_g,   // [B*N,256] bf16 scaled q
    const ushort_t* __restrict__ knv_g,  // [B*N,512] bf16 kn | v
    const ushort_t* __restrict__ kp_g,   // [B][8][256][32] bf16
    const ushort_t* __restrict__ vpT_g,  // [B][8][32][256] bf16
    const ushort_t* __restrict__ vT_g,   // [B][8][32][4096] bf16
    const ushort_t* __restrict__ pbl,    // pool bias, C-frag order
    const float* __restrict__ rpb,       // [8,9]
    const float* __restrict__ qe,        // [8,32]
    const float* __restrict__ temp,      // [8]
    const float* __restrict__ lt,        // [8,32,9]
    const float* __restrict__ lb,        // [8,9]
    ushort_t* __restrict__ outp)         // bf16 [B*N,256]
{
    __shared__ __align__(16) ushort_t qs_lds[64*32];       // 4 KB
    __shared__ __align__(16) ushort_t ltT_lds[16*32];      // 1 KB
    __shared__ __align__(16) ushort_t Wb_lds[4*3*16*40];   // 15 KB
    __shared__ float wloc[64*10];
    __shared__ float wext[64*10];
    __shared__ float invs2[64];
    __shared__ float rpb_lds[9], elb_lds[9];

    // XCD-aware bijective swizzle: lin -> virt (2048 = 8 XCDs x 256)
    const int lin  = blockIdx.x;
    const int virt = (lin & 7) * 256 + (lin >> 3);
    const int tile = virt & 63;          // image row y
    const int hh   = (virt >> 6) & 7;
    const int b    = virt >> 9;

    const int tid  = threadIdx.x;
    const int wv   = tid >> 6;
    const int lane = tid & 63;
    const int la   = lane & 15;
    const int lg   = lane >> 4;
    const int r0   = wv * 16;

    // ---------------- staging ----------------
    {
        int row = tid >> 2, ck = tid & 3;
        short8b v = *(const short8b*)&qs_g[((size_t)(b*N_ + tile*64 + row)) * 256 + hh*32 + ck*8];
        *(short8b*)&qs_lds[row*32 + ((ck ^ (row & 3)) * 8)] = v;
    }
    {
        int l = tid >> 4, dd = (tid & 15) * 2;
        ushort_t a = (l < 9) ? f2bf(lt[hh*288 + dd*9 + l]) : (ushort_t)0;
        ushort_t c = (l < 9) ? f2bf(lt[hh*288 + (dd+1)*9 + l]) : (ushort_t)0;
        ltT_lds[l*32 + dd]   = a;
        ltT_lds[l*32 + dd+1] = c;
    }
    {
        short8b z = {0,0,0,0,0,0,0,0};
        for (int i = tid; i < 960; i += 256) *(short8b*)&Wb_lds[i*8] = z;
    }
    if (tid < 64) {
        int xx = tid;
        int ci = 1 + (tile > 0) + (tile < IMG-1);
        int cj = 1 + (xx > 0) + (xx < IMG-1);
        float sp = log1pf(expf(temp[hh]));
        invs2[tid] = 1.0f / (sp * logf((float)(ci*cj) + (float)PL_));
    }
    if (tid >= 64 && tid < 73) {
        int l = tid - 64;
        float e = 0.f;
        for (int d = 0; d < 32; ++d) e += qe[hh*32 + d] * lt[hh*288 + d*9 + l];
        elb_lds[l] = lb[hh*9 + l] - e;
        rpb_lds[l] = rpb[hh*9 + l];
    }
    __syncthreads();

    const short8b af = *(const short8b*)&qs_lds[(r0+la)*32 + ((lg ^ (la & 3)) * 8)];

    // ---------------- local QK: Gram-band MFMA ----------------
    {
        f32x4 G[3][2];
        const f32x4 zc = {0.f,0.f,0.f,0.f};
        #pragma unroll
        for (int dyi = 0; dyi < 3; ++dyi) {
            int cy = tile + dyi - 1;
            cy = cy < 0 ? 0 : (cy > 63 ? 63 : cy);
            #pragma unroll
            for (int f = 0; f < 2; ++f) {
                int xp = wv*16 - 8 + 16*f + la;
                xp = xp < 0 ? 0 : (xp > 63 ? 63 : xp);
                const short8b kf = *(const short8b*)
                    &knv_g[((size_t)(b*N_ + cy*64 + xp)) * 512 + hh*32 + lg*8];
                G[dyi][f] = __builtin_amdgcn_mfma_f32_16x16x32_bf16(af, kf, zc, 0, 0, 0);
            }
        }
        #pragma unroll
        for (int f = 0; f < 2; ++f)
            #pragma unroll
            for (int reg = 0; reg < 4; ++reg) {
                int r  = lg*4 + reg;
                int dx = la + 16*f - 8 - r;
                if (dx >= -1 && dx <= 1) {
                    #pragma unroll
                    for (int dyi = 0; dyi < 3; ++dyi)
                        wloc[(r0 + r)*10 + dyi*3 + dx + 1] = G[dyi][f][reg];
                }
            }
    }

    // ---------------- extras MFMA: s3 = qs . lt ----------------
    {
        const short8b ltf = *(const short8b*)&ltT_lds[la*32 + lg*8];
        const f32x4 zc = {0.f,0.f,0.f,0.f};
        f32x4 E = __builtin_amdgcn_mfma_f32_16x16x32_bf16(af, ltf, zc, 0, 0, 0);
        if (la < 9) {
            #pragma unroll
            for (int reg = 0; reg < 4; ++reg) {
                int rr = r0 + lg*4 + reg;
                wext[rr*10 + la] = invs2[rr] * E[reg] + elb_lds[la];
            }
        }
    }

    // ---------------- pool QK^T ----------------
    const ushort_t* kph = kp_g + ((size_t)(b*NH + hh) * PL_) * 32;
    const ushort_t* pbw = pbl + ((((size_t)hh * 64 + tile) * 4 + wv) * 4096);

    f32x4 acc[16];
    #pragma unroll
    for (int t = 0; t < 16; ++t) {
        ushort4 b4 = *(const ushort4*)&pbw[t*256 + lg*64 + la*4];
        f32x4 c;
        c[0] = bf2f(b4.x); c[1] = bf2f(b4.y); c[2] = bf2f(b4.z); c[3] = bf2f(b4.w);
        short8b kf = *(const short8b*)&kph[(t*16 + la)*32 + lg*8];
        acc[t] = __builtin_amdgcn_mfma_f32_16x16x32_bf16(kf, af, c, 0, 0, 0);
    }

    // ---------------- joint softmax ----------------
    const int rr = r0 + la;
    float mx = -3.0e38f;
    #pragma unroll
    for (int t = 0; t < 16; ++t)
        #pragma unroll
        for (int reg = 0; reg < 4; ++reg) mx = fmaxf(mx, acc[t][reg]);
    mx = fmaxf(mx, __shfl_xor(mx, 16, 64));
    mx = fmaxf(mx, __shfl_xor(mx, 32, 64));
    float lv[9];
    #pragma unroll
    for (int l = 0; l < 9; ++l) {
        int dy = l/3 - 1, dx = l%3 - 1;
        int yy = tile + dy, xx = rr + dx;
        bool val = (yy >= 0 && yy < IMG && xx >= 0 && xx < IMG);
        lv[l] = val ? (wloc[rr*10 + l] + rpb_lds[l]) : -1e9f;
        mx = fmaxf(mx, lv[l]);
    }

    float s = 0.f;
    #pragma unroll
    for (int t = 0; t < 16; ++t)
        #pragma unroll
        for (int reg = 0; reg < 4; ++reg) {
            float e = __expf(acc[t][reg] - mx);
            acc[t][reg] = e;
            s += e;
        }
    s += __shfl_xor(s, 16, 64);
    s += __shfl_xor(s, 32, 64);
    float sl = 0.f;
    float el[9];
    #pragma unroll
    for (int l = 0; l < 9; ++l) { el[l] = __expf(lv[l] - mx); sl += el[l]; }
    s += sl;
    const float inv = 1.f / s;

    if (lg == 0) {
        #pragma unroll
        for (int l = 0; l < 9; ++l) {
            int dy = l/3 - 1, dx = l%3 - 1;
            int yy = tile + dy, xx = rr + dx;
            bool val = (yy >= 0 && yy < IMG && xx >= 0 && xx < IMG);
            float wl = el[l]*inv + wext[rr*10 + l];
            Wb_lds[((wv*3 + l/3)*16 + la)*40 + (la + 8 + dx)] =
                val ? f2bf(wl) : (ushort_t)0;
        }
    }

    // ---------------- PV ----------------
    f32x4 o0 = {0.f,0.f,0.f,0.f}, o1 = {0.f,0.f,0.f,0.f};

    {   // local: per dy, A=Wb[wv][dy], B=vT window
        const ushort_t* vTh = vT_g + (size_t)(b*NH + hh) * 32 * N_;
        #pragma unroll
        for (int dyi = 0; dyi < 3; ++dyi) {
            int cy = tile + dyi - 1;
            cy = cy < 0 ? 0 : (cy > 63 ? 63 : cy);
            int nb = cy*64 + wv*16 - 8 + lg*8;
            nb = nb < 0 ? 0 : (nb > (N_ - 8) ? (N_ - 8) : nb);
            short8b wf = *(const short8b*)&Wb_lds[((wv*3 + dyi)*16 + la)*40 + lg*8];
            short8b vf0 = *(const short8b*)&vTh[(size_t)la * N_ + nb];
            short8b vf1 = *(const short8b*)&vTh[(size_t)(16 + la) * N_ + nb];
            o0 = __builtin_amdgcn_mfma_f32_16x16x32_bf16(wf, vf0, o0, 0, 0, 0);
            o1 = __builtin_amdgcn_mfma_f32_16x16x32_bf16(wf, vf1, o1, 0, 0, 0);
        }
    }

    {   // pool PV: shuffle-permuted A-frags
        const int src0 = la + 32*(lg & 1);
        const int src1 = src0 + 16;
        const bool hi  = (lg >= 2);
        const ushort_t* vph = vpT_g + ((size_t)(b*NH + hh) * 32) * 256;
        #pragma unroll
        for (int kk = 0; kk < 8; ++kk) {
            unsigned A0 = pk2(acc[2*kk][0]*inv,   acc[2*kk][1]*inv);
            unsigned A1 = pk2(acc[2*kk][2]*inv,   acc[2*kk][3]*inv);
            unsigned B0 = pk2(acc[2*kk+1][0]*inv, acc[2*kk+1][1]*inv);
            unsigned B1 = pk2(acc[2*kk+1][2]*inv, acc[2*kk+1][3]*inv);
            unsigned xa0 = __shfl(A0, src0, 64), xb0 = __shfl(B0, src0, 64);
            unsigned xa1 = __shfl(A1, src0, 64), xb1 = __shfl(B1, src0, 64);
            unsigned ya0 = __shfl(A0, src1, 64), yb0 = __shfl(B0, src1, 64);
            unsigned ya1 = __shfl(A1, src1, 64), yb1 = __shfl(B1, src1, 64);
            union { unsigned u[4]; short8b v; } wf;
            wf.u[0] = hi ? xb0 : xa0;
            wf.u[1] = hi ? xb1 : xa1;
            wf.u[2] = hi ? yb0 : ya0;
            wf.u[3] = hi ? yb1 : ya1;
            short8b vf0 = *(const short8b*)&vph[(size_t)la*256      + kk*32 + lg*8];
            short8b vf1 = *(const short8b*)&vph[(size_t)(16+la)*256 + kk*32 + lg*8];
            o0 = __builtin_amdgcn_mfma_f32_16x16x32_bf16(wf.v, vf0, o0, 0, 0, 0);
            o1 = __builtin_amdgcn_mfma_f32_16x16x32_bf16(wf.v, vf1, o1, 0, 0, 0);
        }
    }

    #pragma unroll
    for (int reg = 0; reg < 4; ++reg) {
        int r2 = r0 + lg*4 + reg;
        int n  = tile*64 + r2;
        ushort_t* orow = outp + ((size_t)(b*N_ + n)) * C_ + hh*32;
        orow[la]      = f2bf(o0[reg]);
        orow[16 + la] = f2bf(o1[reg]);
    }
}

// ---------------------------------------------------------------------------
extern "C" void kernel_launch(void* const* d_in, const int* in_sizes, int n_in,
                              void* d_out, int out_size, void* d_ws, size_t ws_size,
                              hipStream_t stream) {
    const float* x    = (const float*)d_in[0];
    const float* rct  = (const float*)d_in[1];
    const int*   rpi  = (const int*)  d_in[2];
    const float* q_w  = (const float*)d_in[3];
    const float* q_b  = (const float*)d_in[4];
    const float* kv_w = (const float*)d_in[5];
    const float* kv_b = (const float*)d_in[6];
    const float* temp = (const float*)d_in[7];
    const float* qe   = (const float*)d_in[8];
    const float* sr_w = (const float*)d_in[9];
    const float* sr_b = (const float*)d_in[10];
    const float* ng   = (const float*)d_in[11];
    const float* nb   = (const float*)d_in[12];
    const float* c1w  = (const float*)d_in[13];
    const float* c1b  = (const float*)d_in[14];
    const float* c2w  = (const float*)d_in[15];
    const float* c2b  = (const float*)d_in[16];
    const float* rpb  = (const float*)d_in[17];
    const float* lt   = (const float*)d_in[18];
    const float* lb   = (const float*)d_in[19];
    const float* p_w  = (const float*)d_in[20];
    const float* p_b  = (const float*)d_in[21];
    float* out = (float*)d_out;

    float* ws = (float*)d_ws;
    const size_t MN = (size_t)B_ * N_;               // 16384
    float* buf_sr  = ws;                             // [MN,256] f32
    float* buf_t   = buf_sr + MN * 256;              // [8,1024]
    ushort_t* x_bf   = (ushort_t*)(buf_t + 8*1024);  // [MN,256]
    ushort_t* pre_bf = x_bf   + MN * 256;            // [MN,256] attn out
    ushort_t* WTall  = pre_bf + MN * 256;            // [1024,256]
    ushort_t* pwT    = WTall  + 1024*256;            // [256,256]
    ushort_t* qs_bf  = pwT    + 256*256;             // [MN,256]
    ushort_t* knv_bf = qs_bf  + MN * 256;            // [MN,512]
    ushort_t* kp_bf  = knv_bf + MN * 512;            // [B*8*256*32]
    ushort_t* vpT_bf = kp_bf  + (size_t)B_*NH*PL_*32;// [B*8*32*256]
    ushort_t* vT_bf  = vpT_bf + (size_t)B_*NH*32*PL_;// [B*8*32*4096]
    ushort_t* pbl    = vT_bf  + (size_t)B_*NH*32*N_; // [2097152*4]
    ushort_t* xs_bf  = pbl    + (size_t)2097152*4;   // [B*PL,256]

    const int M = (int)MN;  // 16384

    // 1: x convert + weight transposes + CPB MLP
    prep_all<<<2464, 256, 0, stream>>>(x, q_w, kv_w, sr_w, p_w, rct,
                                       c1w, c1b, c2w, c2b, x_bf, WTall, pwT, buf_t);
    // 2: fused q|kv|sr GEMM with pb-gather blocks INTERLEAVED (1D grid)
    gemm_fused<<<10240, 256, 0, stream>>>(x_bf, WTall, q_b, kv_b, sr_b,
                                          temp, qe, rpi, buf_t, pbl,
                                          qs_bf, knv_bf, buf_sr);
    // 3: pool_ln + vtrans
    mid_prep<<<1536, 256, 0, stream>>>(knv_bf, buf_sr, ng, nb, xs_bf, vT_bf);
    // 4: pooled kv GEMM with fused norm/transpose epilogue
    gemm_kvp<<<dim3(8, 8), 256, 0, stream>>>(xs_bf, WTall + 256*256, kv_b,
                                             kp_bf, vpT_bf);
    // 5: attention (validated r12 body: 1 tile/block, XCD swizzle, no bound)
    attn_v4<<<2048, 256, 0, stream>>>(qs_bf, knv_bf, kp_bf, vpT_bf, vT_bf,
                                      pbl, rpb, qe, temp, lt, lb, pre_bf);
    // 6: output projection
    gemm_mfma<0><<<dim3(4, M/128), 256, 0, stream>>>(pre_bf, pwT, p_b, out, M, 256);
}

// Round 15
// 130.470 us; speedup vs baseline: 1.6298x; 1.0364x over previous
//
#include <hip/hip_runtime.h>
#include <math.h>

#define B_   4
#define N_   4096
#define C_   256
#define NH   8      // heads
#define D_   32     // head dim
#define PL_  256    // pooled length
#define IMG  64     // H = W = 64

typedef __attribute__((ext_vector_type(8))) short short8b;
typedef __attribute__((ext_vector_type(4))) float f32x4;
typedef unsigned short ushort_t;

__device__ __forceinline__ ushort_t f2bf(float f) {
    unsigned u = __float_as_uint(f);
    u += 0x7FFFu + ((u >> 16) & 1u);   // RTNE
    return (ushort_t)(u >> 16);
}
__device__ __forceinline__ float bf2f(ushort_t s) {
    return __uint_as_float(((unsigned)s) << 16);
}
__device__ __forceinline__ unsigned pk2(float lo, float hi) {
    return (unsigned)f2bf(lo) | ((unsigned)f2bf(hi) << 16);
}
__device__ __forceinline__ float gelu_f(float v) {
    return 0.5f * v * (1.0f + erff(v * 0.70710678118654752440f));
}

// ---------------------------------------------------------------------------
// prep_all (validated round 9): x->bf16 + weight transposes + CPB MLP.
// ---------------------------------------------------------------------------
__global__ __launch_bounds__(256) void prep_all(const float* __restrict__ x,
                                                const float* __restrict__ q_w,
                                                const float* __restrict__ kv_w,
                                                const float* __restrict__ sr_w,
                                                const float* __restrict__ p_w,
                                                const float* __restrict__ rct,
                                                const float* __restrict__ c1w,
                                                const float* __restrict__ c1b,
                                                const float* __restrict__ c2w,
                                                const float* __restrict__ c2b,
                                                ushort_t* __restrict__ x_bf,
                                                ushort_t* __restrict__ WTall,
                                                ushort_t* __restrict__ pwT,
                                                float* __restrict__ tT)
{
    const int blk = blockIdx.x;
    const int tid = threadIdx.x;
    if (blk < 2048) {
        int gid = blk * 256 + tid;
        const float4* p = (const float4*)(x + (size_t)gid * 8);
        float4 v0 = p[0], v1 = p[1];
        short8b o;
        o[0]=(short)f2bf(v0.x); o[1]=(short)f2bf(v0.y);
        o[2]=(short)f2bf(v0.z); o[3]=(short)f2bf(v0.w);
        o[4]=(short)f2bf(v1.x); o[5]=(short)f2bf(v1.y);
        o[6]=(short)f2bf(v1.z); o[7]=(short)f2bf(v1.w);
        *(short8b*)&x_bf[(size_t)gid * 8] = o;
    } else if (blk < 2208) {
        int wt = (blk - 2048) * 256 + tid;   // 0..40959
        int row = wt >> 5;                   // 0..1279
        int k0  = (wt & 31) << 3;
        const float* W; int N, n; ushort_t* dst;
        if (row < 256)       { W = q_w;  N = 256; n = row;        dst = WTall + (size_t)row * 256; }
        else if (row < 768)  { W = kv_w; N = 512; n = row - 256;  dst = WTall + (size_t)row * 256; }
        else if (row < 1024) { W = sr_w; N = 256; n = row - 768;  dst = WTall + (size_t)row * 256; }
        else                 { W = p_w;  N = 256; n = row - 1024; dst = pwT + (size_t)(row-1024) * 256; }
        short8b v;
        #pragma unroll
        for (int j = 0; j < 8; ++j) v[j] = (short)f2bf(W[(size_t)(k0 + j) * N + n]);
        *(short8b*)&dst[k0] = v;
    } else {
        int l = (blk - 2208) * 4 + (tid >> 6);
        int lane = tid & 63;
        float c0 = rct[l*2+0], c1 = rct[l*2+1];
        float acc[8] = {0,0,0,0,0,0,0,0};
        for (int j = lane; j < 512; j += 64) {
            float hv = fmaxf(c0 * c1w[j] + c1 * c1w[512+j] + c1b[j], 0.f);
            #pragma unroll
            for (int hh = 0; hh < 8; ++hh) acc[hh] += hv * c2w[j*8 + hh];
        }
        #pragma unroll
        for (int o = 32; o > 0; o >>= 1)
            #pragma unroll
            for (int hh = 0; hh < 8; ++hh) acc[hh] += __shfl_xor(acc[hh], o, 64);
        if (lane < 8) tT[lane * 1024 + l] = acc[lane] + c2b[lane];
    }
}

// ---------------------------------------------------------------------------
// gemm_fused (validated round 12, best-measured config): by<128 = GEMM with
// in-register norm epilogue; by>=128 = pb-gather blocks.
// ---------------------------------------------------------------------------
__global__ __launch_bounds__(256) void gemm_fused(const ushort_t* __restrict__ Abf,
                                                  const ushort_t* __restrict__ WTall,
                                                  const float* __restrict__ q_b,
                                                  const float* __restrict__ kv_b,
                                                  const float* __restrict__ sr_b,
                                                  const float* __restrict__ temp,
                                                  const float* __restrict__ qe,
                                                  const int* __restrict__ rpi,
                                                  const float* __restrict__ tT,
                                                  ushort_t* __restrict__ pbl,
                                                  ushort_t* __restrict__ qs_bf,
                                                  ushort_t* __restrict__ knv_bf,
                                                  float* __restrict__ buf_sr)
{
    __shared__ __align__(16) ushort_t Bs[64 * 256];   // 32 KB

    const int tid = threadIdx.x;

    if (blockIdx.y >= 128) {     // ---- pb gather ----
        int pbid = (blockIdx.y - 128) * 16 + blockIdx.x;   // 0..8191
        int gid = pbid * 256 + tid;
        int la   = gid & 15;
        int lg   = (gid >> 4) & 3;
        int t    = (gid >> 6) & 15;
        int wv   = (gid >> 10) & 3;
        int tile = (gid >> 12) & 63;
        int h    = gid >> 18;
        int n  = tile * 64 + wv * 16 + la;
        int p0 = t * 16 + lg * 4;
        int4 r = *(const int4*)&rpi[(size_t)n * PL_ + p0];
        const float* tTh = tT + h * 1024;
        ushort4 o;
        o.x = f2bf(tTh[r.x]);
        o.y = f2bf(tTh[r.y]);
        o.z = f2bf(tTh[r.z]);
        o.w = f2bf(tTh[r.w]);
        *(ushort4*)&pbl[(size_t)gid * 4] = o;
        return;
    }

    const int wv   = tid >> 6;
    const int lane = tid & 63;
    const int la   = lane & 15, lg = lane >> 4;
    const int m0   = blockIdx.y * 128 + wv * 32;
    const int bx   = blockIdx.x;
    const int n0   = bx * 64;

    {
        const int srow = tid >> 2, sm = tid & 3;
        const ushort_t* wrow = WTall + (size_t)(n0 + srow) * 256;
        #pragma unroll
        for (int c8 = 0; c8 < 8; ++c8) {
            int ck = c8 * 4 + sm;
            short8b v = *(const short8b*)&wrow[ck * 8];
            *(short8b*)&Bs[srow * 256 + ((ck ^ (srow & 3)) * 8)] = v;
        }
    }
    __syncthreads();

    const ushort_t* a0p = Abf + (size_t)(m0 + la) * 256 + lg * 8;
    const ushort_t* a1p = a0p + (size_t)16 * 256;

    f32x4 acc[2][4];
    #pragma unroll
    for (int i = 0; i < 2; ++i)
        #pragma unroll
        for (int j = 0; j < 4; ++j) acc[i][j] = (f32x4){0.f, 0.f, 0.f, 0.f};

    #pragma unroll
    for (int kit = 0; kit < 8; ++kit) {
        short8b a0 = *(const short8b*)(a0p + kit * 32);
        short8b a1 = *(const short8b*)(a1p + kit * 32);
        #pragma unroll
        for (int nf = 0; nf < 4; ++nf) {
            int brow = nf * 16 + la;
            short8b bb = *(const short8b*)&Bs[brow * 256 + (((kit*4 + lg) ^ (la & 3)) * 8)];
            acc[0][nf] = __builtin_amdgcn_mfma_f32_16x16x32_bf16(a0, bb, acc[0][nf], 0, 0, 0);
            acc[1][nf] = __builtin_amdgcn_mfma_f32_16x16x32_bf16(a1, bb, acc[1][nf], 0, 0, 0);
        }
    }

    if (bx < 8) {
        const float* bias = (bx < 4) ? q_b : kv_b;
        const int cb = (bx < 4) ? n0 : (n0 - 256);
        float bv[4];
        #pragma unroll
        for (int nf = 0; nf < 4; ++nf) bv[nf] = bias[cb + nf*16 + la];
        float sp0 = 0.f, sp1 = 0.f;
        if (bx < 4) {
            sp0 = log1pf(expf(temp[bx*2 + 0]));
            sp1 = log1pf(expf(temp[bx*2 + 1]));
        }
        #pragma unroll
        for (int mf = 0; mf < 2; ++mf)
            #pragma unroll
            for (int reg = 0; reg < 4; ++reg) {
                int m = m0 + mf*16 + lg*4 + reg;
                #pragma unroll
                for (int h2 = 0; h2 < 2; ++h2) {
                    float v0 = acc[mf][2*h2][reg]   + bv[2*h2];
                    float v1 = acc[mf][2*h2+1][reg] + bv[2*h2+1];
                    float ss = v0*v0 + v1*v1;
                    ss += __shfl_xor(ss, 1, 64);
                    ss += __shfl_xor(ss, 2, 64);
                    ss += __shfl_xor(ss, 4, 64);
                    ss += __shfl_xor(ss, 8, 64);
                    float inv = rsqrtf(ss + 1e-12f);
                    if (bx < 4) {
                        int head = bx*2 + h2;
                        int n = m & (N_-1);
                        int y = n >> 6, xc = n & 63;
                        int cnt = (1 + (y > 0) + (y < IMG-1)) * (1 + (xc > 0) + (xc < IMG-1));
                        float lc = (cnt == 4) ? 5.5606816f : (cnt == 6) ? 5.5683445f : 5.5797298f;
                        float s2 = (h2 ? sp1 : sp0) * lc;
                        ushort_t* dst = qs_bf + (size_t)m * 256 + head*32;
                        dst[la]      = f2bf((v0*inv + qe[head*32 + la])      * s2);
                        dst[16 + la] = f2bf((v1*inv + qe[head*32 + 16 + la]) * s2);
                    } else {
                        int head = (bx-4)*2 + h2;
                        ushort_t* dst = knv_bf + (size_t)m * 512 + head*32;
                        dst[la]      = f2bf(v0*inv);
                        dst[16 + la] = f2bf(v1*inv);
                    }
                }
            }
    } else if (bx < 12) {
        #pragma unroll
        for (int mf = 0; mf < 2; ++mf)
            #pragma unroll
            for (int nf = 0; nf < 4; ++nf)
                #pragma unroll
                for (int reg = 0; reg < 4; ++reg) {
                    int m = m0 + mf*16 + lg*4 + reg;
                    int col_kv = n0 - 256 + nf*16 + la;
                    knv_bf[(size_t)m * 512 + col_kv] =
                        f2bf(acc[mf][nf][reg] + kv_b[col_kv]);
                }
    } else {
        #pragma unroll
        for (int mf = 0; mf < 2; ++mf)
            #pragma unroll
            for (int nf = 0; nf < 4; ++nf)
                #pragma unroll
                for (int reg = 0; reg < 4; ++reg) {
                    int m = m0 + mf*16 + lg*4 + reg;
                    int c = n0 + nf*16 + la - 768;
                    buf_sr[(size_t)m * 256 + c] = gelu_f(acc[mf][nf][reg] + sr_b[c]);
                }
    }
}

// ---------------------------------------------------------------------------
// mid_prep v3: pool_ln only (1024 blocks). vtrans moved into gemm_kvp_vt.
// ---------------------------------------------------------------------------
__global__ __launch_bounds__(256) void mid_prep(const float* __restrict__ sr,
                                                const float* __restrict__ g,
                                                const float* __restrict__ bb,
                                                ushort_t* __restrict__ xs)
{
    __shared__ float red[256];
    int bp = blockIdx.x;
    int b = bp >> 8, p = bp & 255;
    int i0 = p >> 4, j0 = p & 15;
    int c = threadIdx.x;
    float s = 0.f;
    #pragma unroll
    for (int di = 0; di < 4; ++di)
        #pragma unroll
        for (int dj = 0; dj < 4; ++dj) {
            int n = (i0*4 + di) * IMG + (j0*4 + dj);
            s += sr[((size_t)b * N_ + n) * C_ + c];
        }
    s *= (1.f / 16.f);
    red[c] = s; __syncthreads();
    for (int o = 128; o > 0; o >>= 1) { if (c < o) red[c] += red[c+o]; __syncthreads(); }
    float mean = red[0] * (1.f/256.f);
    __syncthreads();
    float dcen = s - mean;
    red[c] = dcen * dcen; __syncthreads();
    for (int o = 128; o > 0; o >>= 1) { if (c < o) red[c] += red[c+o]; __syncthreads(); }
    float var = red[0] * (1.f/256.f);
    float outv = dcen * rsqrtf(var + 1e-5f) * g[c] + bb[c];
    xs[(size_t)bp * C_ + c] = f2bf(outv);
}

// ---------------------------------------------------------------------------
// gemm_kvp_vt: 1D grid 576. id<64 = pooled-kv GEMM with fused norm/transpose
// epilogue (validated r11, bx=id&7, by=id>>3); id>=64 = vtrans block
// (validated mid_prep code) — overlaps with the tiny GEMM.
// ---------------------------------------------------------------------------
__global__ __launch_bounds__(256) void gemm_kvp_vt(const ushort_t* __restrict__ Abf,
                                                   const ushort_t* __restrict__ WT,
                                                   const float* __restrict__ kv_b,
                                                   const ushort_t* __restrict__ knv,
                                                   ushort_t* __restrict__ kp_bf,
                                                   ushort_t* __restrict__ vpT_bf,
                                                   ushort_t* __restrict__ vT)
{
    __shared__ __align__(16) ushort_t Bs[64 * 256];   // 32 KB (vtrans uses 20 KB)

    const int id  = blockIdx.x;
    const int tid = threadIdx.x;

    if (id >= 64) {              // ---- vtrans ----
        ushort_t (*ts)[40] = (ushort_t (*)[40])Bs;
        int vb = id - 64;
        int nt = vb & 15, bh = vb >> 4;
        const ushort_t* src = knv + ((size_t)((bh >> 3)*N_ + nt*256 + tid)) * 512 + 256 + (bh & 7)*32;
        #pragma unroll
        for (int c = 0; c < 4; ++c)
            *(short8b*)&ts[tid][c*8] = *(const short8b*)&src[c*8];
        __syncthreads();
        int d = tid >> 3, cc = tid & 7;
        ushort_t* dst = vT + ((size_t)bh*32 + d) * (size_t)N_ + nt*256;
        #pragma unroll
        for (int k = 0; k < 4; ++k) {
            int n0 = cc*32 + k*8;
            short8b v;
            #pragma unroll
            for (int j = 0; j < 8; ++j) v[j] = ts[n0+j][d];
            *(short8b*)&dst[n0] = v;
        }
        return;
    }

    const int wv   = tid >> 6;
    const int lane = tid & 63;
    const int la   = lane & 15, lg = lane >> 4;
    const int bx   = id & 7;
    const int m0   = (id >> 3) * 128 + wv * 32;
    const int n0   = bx * 64;

    {
        const int srow = tid >> 2, sm = tid & 3;
        const ushort_t* wrow = WT + (size_t)(n0 + srow) * 256;
        #pragma unroll
        for (int c8 = 0; c8 < 8; ++c8) {
            int ck = c8 * 4 + sm;
            short8b v = *(const short8b*)&wrow[ck * 8];
            *(short8b*)&Bs[srow * 256 + ((ck ^ (srow & 3)) * 8)] = v;
        }
    }
    __syncthreads();

    const ushort_t* a0p = Abf + (size_t)(m0 + la) * 256 + lg * 8;
    const ushort_t* a1p = a0p + (size_t)16 * 256;

    f32x4 acc[2][4];
    #pragma unroll
    for (int i = 0; i < 2; ++i)
        #pragma unroll
        for (int j = 0; j < 4; ++j) acc[i][j] = (f32x4){0.f, 0.f, 0.f, 0.f};

    #pragma unroll
    for (int kit = 0; kit < 8; ++kit) {
        short8b a0 = *(const short8b*)(a0p + kit * 32);
        short8b a1 = *(const short8b*)(a1p + kit * 32);
        #pragma unroll
        for (int nf = 0; nf < 4; ++nf) {
            int brow = nf * 16 + la;
            short8b bb = *(const short8b*)&Bs[brow * 256 + (((kit*4 + lg) ^ (la & 3)) * 8)];
            acc[0][nf] = __builtin_amdgcn_mfma_f32_16x16x32_bf16(a0, bb, acc[0][nf], 0, 0, 0);
            acc[1][nf] = __builtin_amdgcn_mfma_f32_16x16x32_bf16(a1, bb, acc[1][nf], 0, 0, 0);
        }
    }

    if (bx < 4) {
        float bv[4];
        #pragma unroll
        for (int nf = 0; nf < 4; ++nf) bv[nf] = kv_b[n0 + nf*16 + la];
        #pragma unroll
        for (int mf = 0; mf < 2; ++mf)
            #pragma unroll
            for (int reg = 0; reg < 4; ++reg) {
                int m = m0 + mf*16 + lg*4 + reg;
                int b = m >> 8, p = m & 255;
                #pragma unroll
                for (int h2 = 0; h2 < 2; ++h2) {
                    float v0 = acc[mf][2*h2][reg]   + bv[2*h2];
                    float v1 = acc[mf][2*h2+1][reg] + bv[2*h2+1];
                    float ss = v0*v0 + v1*v1;
                    ss += __shfl_xor(ss, 1, 64);
                    ss += __shfl_xor(ss, 2, 64);
                    ss += __shfl_xor(ss, 4, 64);
                    ss += __shfl_xor(ss, 8, 64);
                    float inv = rsqrtf(ss + 1e-12f);
                    int head = bx*2 + h2;
                    ushort_t* dst = kp_bf + (((size_t)(b*NH + head)) * PL_ + p) * 32;
                    dst[la]      = f2bf(v0*inv);
                    dst[16 + la] = f2bf(v1*inv);
                }
            }
    } else {
        #pragma unroll
        for (int mf = 0; mf < 2; ++mf)
            #pragma unroll
            for (int nf = 0; nf < 4; ++nf)
                #pragma unroll
                for (int reg = 0; reg < 4; ++reg) {
                    int m = m0 + mf*16 + lg*4 + reg;
                    int b = m >> 8, p = m & 255;
                    int col_kv = n0 + nf*16 + la;       // [256,512)
                    int cv = col_kv - 256;
                    int head = cv >> 5, d = cv & 31;
                    vpT_bf[(((size_t)(b*NH + head)) * 32 + d) * 256 + p] =
                        f2bf(acc[mf][nf][reg] + kv_b[col_kv]);
                }
    }
}

// ---------------------------------------------------------------------------
// Generic bf16 MFMA GEMM, K=256 (validated): proj.
// ---------------------------------------------------------------------------
template<int ACT>
__global__ __launch_bounds__(256) void gemm_mfma(const ushort_t* __restrict__ Abf,
                                                 const ushort_t* __restrict__ WT,
                                                 const float* __restrict__ bias,
                                                 float* __restrict__ out,
                                                 int M, int N)
{
    __shared__ __align__(16) ushort_t Bs[64 * 256];

    const int tid  = threadIdx.x;
    const int wv   = tid >> 6;
    const int lane = tid & 63;
    const int la   = lane & 15, lg = lane >> 4;
    const int m0   = blockIdx.y * 128 + wv * 32;
    const int n0   = blockIdx.x * 64;

    {
        const int srow = tid >> 2, sm = tid & 3;
        const ushort_t* wrow = WT + (size_t)(n0 + srow) * 256;
        #pragma unroll
        for (int c8 = 0; c8 < 8; ++c8) {
            int ck = c8 * 4 + sm;
            short8b v = *(const short8b*)&wrow[ck * 8];
            *(short8b*)&Bs[srow * 256 + ((ck ^ (srow & 3)) * 8)] = v;
        }
    }
    __syncthreads();

    const ushort_t* a0p = Abf + (size_t)(m0 + la) * 256 + lg * 8;
    const ushort_t* a1p = a0p + (size_t)16 * 256;

    f32x4 acc[2][4];
    #pragma unroll
    for (int i = 0; i < 2; ++i)
        #pragma unroll
        for (int j = 0; j < 4; ++j) acc[i][j] = (f32x4){0.f, 0.f, 0.f, 0.f};

    #pragma unroll
    for (int kit = 0; kit < 8; ++kit) {
        short8b a0 = *(const short8b*)(a0p + kit * 32);
        short8b a1 = *(const short8b*)(a1p + kit * 32);
        #pragma unroll
        for (int nf = 0; nf < 4; ++nf) {
            int brow = nf * 16 + la;
            short8b bb = *(const short8b*)&Bs[brow * 256 + (((kit*4 + lg) ^ (la & 3)) * 8)];
            acc[0][nf] = __builtin_amdgcn_mfma_f32_16x16x32_bf16(a0, bb, acc[0][nf], 0, 0, 0);
            acc[1][nf] = __builtin_amdgcn_mfma_f32_16x16x32_bf16(a1, bb, acc[1][nf], 0, 0, 0);
        }
    }
    #pragma unroll
    for (int mf = 0; mf < 2; ++mf)
        #pragma unroll
        for (int nf = 0; nf < 4; ++nf)
            #pragma unroll
            for (int reg = 0; reg < 4; ++reg) {
                int m  = m0 + mf * 16 + lg * 4 + reg;
                int nn = n0 + nf * 16 + la;
                float v = acc[mf][nf][reg] + bias[nn];
                if (ACT == 1) v = gelu_f(v);
                out[(size_t)m * N + nn] = v;
            }
}

// ---------------------------------------------------------------------------
// attn_v4 (validated rounds 8/10/12/14, ~53.5 µs): single tile per block,
// XCD swizzle, no min-waves launch bound.
// ---------------------------------------------------------------------------
__global__ __launch_bounds__(256) void attn_v4(
    const ushort_t* __restrict__ qs_g,   // [B*N,256] bf16 scaled q
    const ushort_t* __restrict__ knv_g,  // [B*N,512] bf16 kn | v
    const ushort_t* __restrict__ kp_g,   // [B][8][256][32] bf16
    const ushort_t* __restrict__ vpT_g,  // [B][8][32][256] bf16
    const ushort_t* __restrict__ vT_g,   // [B][8][32][4096] bf16
    const ushort_t* __restrict__ pbl,    // pool bias, C-frag order
    const float* __restrict__ rpb,       // [8,9]
    const float* __restrict__ qe,        // [8,32]
    const float* __restrict__ temp,      // [8]
    const float* __restrict__ lt,        // [8,32,9]
    const float* __restrict__ lb,        // [8,9]
    ushort_t* __restrict__ outp)         // bf16 [B*N,256]
{
    __shared__ __align__(16) ushort_t qs_lds[64*32];       // 4 KB
    __shared__ __align__(16) ushort_t ltT_lds[16*32];      // 1 KB
    __shared__ __align__(16) ushort_t Wb_lds[4*3*16*40];   // 15 KB
    __shared__ float wloc[64*10];
    __shared__ float wext[64*10];
    __shared__ float invs2[64];
    __shared__ float rpb_lds[9], elb_lds[9];

    // XCD-aware bijective swizzle: lin -> virt (2048 = 8 XCDs x 256)
    const int lin  = blockIdx.x;
    const int virt = (lin & 7) * 256 + (lin >> 3);
    const int tile = virt & 63;          // image row y
    const int hh   = (virt >> 6) & 7;
    const int b    = virt >> 9;

    const int tid  = threadIdx.x;
    const int wv   = tid >> 6;
    const int lane = tid & 63;
    const int la   = lane & 15;
    const int lg   = lane >> 4;
    const int r0   = wv * 16;

    // ---------------- staging ----------------
    {
        int row = tid >> 2, ck = tid & 3;
        short8b v = *(const short8b*)&qs_g[((size_t)(b*N_ + tile*64 + row)) * 256 + hh*32 + ck*8];
        *(short8b*)&qs_lds[row*32 + ((ck ^ (row & 3)) * 8)] = v;
    }
    {
        int l = tid >> 4, dd = (tid & 15) * 2;
        ushort_t a = (l < 9) ? f2bf(lt[hh*288 + dd*9 + l]) : (ushort_t)0;
        ushort_t c = (l < 9) ? f2bf(lt[hh*288 + (dd+1)*9 + l]) : (ushort_t)0;
        ltT_lds[l*32 + dd]   = a;
        ltT_lds[l*32 + dd+1] = c;
    }
    {
        short8b z = {0,0,0,0,0,0,0,0};
        for (int i = tid; i < 960; i += 256) *(short8b*)&Wb_lds[i*8] = z;
    }
    if (tid < 64) {
        int xx = tid;
        int ci = 1 + (tile > 0) + (tile < IMG-1);
        int cj = 1 + (xx > 0) + (xx < IMG-1);
        float sp = log1pf(expf(temp[hh]));
        invs2[tid] = 1.0f / (sp * logf((float)(ci*cj) + (float)PL_));
    }
    if (tid >= 64 && tid < 73) {
        int l = tid - 64;
        float e = 0.f;
        for (int d = 0; d < 32; ++d) e += qe[hh*32 + d] * lt[hh*288 + d*9 + l];
        elb_lds[l] = lb[hh*9 + l] - e;
        rpb_lds[l] = rpb[hh*9 + l];
    }
    __syncthreads();

    const short8b af = *(const short8b*)&qs_lds[(r0+la)*32 + ((lg ^ (la & 3)) * 8)];

    // ---------------- local QK: Gram-band MFMA ----------------
    {
        f32x4 G[3][2];
        const f32x4 zc = {0.f,0.f,0.f,0.f};
        #pragma unroll
        for (int dyi = 0; dyi < 3; ++dyi) {
            int cy = tile + dyi - 1;
            cy = cy < 0 ? 0 : (cy > 63 ? 63 : cy);
            #pragma unroll
            for (int f = 0; f < 2; ++f) {
                int xp = wv*16 - 8 + 16*f + la;
                xp = xp < 0 ? 0 : (xp > 63 ? 63 : xp);
                const short8b kf = *(const short8b*)
                    &knv_g[((size_t)(b*N_ + cy*64 + xp)) * 512 + hh*32 + lg*8];
                G[dyi][f] = __builtin_amdgcn_mfma_f32_16x16x32_bf16(af, kf, zc, 0, 0, 0);
            }
        }
        #pragma unroll
        for (int f = 0; f < 2; ++f)
            #pragma unroll
            for (int reg = 0; reg < 4; ++reg) {
                int r  = lg*4 + reg;
                int dx = la + 16*f - 8 - r;
                if (dx >= -1 && dx <= 1) {
                    #pragma unroll
                    for (int dyi = 0; dyi < 3; ++dyi)
                        wloc[(r0 + r)*10 + dyi*3 + dx + 1] = G[dyi][f][reg];
                }
            }
    }

    // ---------------- extras MFMA: s3 = qs . lt ----------------
    {
        const short8b ltf = *(const short8b*)&ltT_lds[la*32 + lg*8];
        const f32x4 zc = {0.f,0.f,0.f,0.f};
        f32x4 E = __builtin_amdgcn_mfma_f32_16x16x32_bf16(af, ltf, zc, 0, 0, 0);
        if (la < 9) {
            #pragma unroll
            for (int reg = 0; reg < 4; ++reg) {
                int rr = r0 + lg*4 + reg;
                wext[rr*10 + la] = invs2[rr] * E[reg] + elb_lds[la];
            }
        }
    }

    // ---------------- pool QK^T ----------------
    const ushort_t* kph = kp_g + ((size_t)(b*NH + hh) * PL_) * 32;
    const ushort_t* pbw = pbl + ((((size_t)hh * 64 + tile) * 4 + wv) * 4096);

    f32x4 acc[16];
    #pragma unroll
    for (int t = 0; t < 16; ++t) {
        ushort4 b4 = *(const ushort4*)&pbw[t*256 + lg*64 + la*4];
        f32x4 c;
        c[0] = bf2f(b4.x); c[1] = bf2f(b4.y); c[2] = bf2f(b4.z); c[3] = bf2f(b4.w);
        short8b kf = *(const short8b*)&kph[(t*16 + la)*32 + lg*8];
        acc[t] = __builtin_amdgcn_mfma_f32_16x16x32_bf16(kf, af, c, 0, 0, 0);
    }

    // ---------------- joint softmax ----------------
    const int rr = r0 + la;
    float mx = -3.0e38f;
    #pragma unroll
    for (int t = 0; t < 16; ++t)
        #pragma unroll
        for (int reg = 0; reg < 4; ++reg) mx = fmaxf(mx, acc[t][reg]);
    mx = fmaxf(mx, __shfl_xor(mx, 16, 64));
    mx = fmaxf(mx, __shfl_xor(mx, 32, 64));
    float lv[9];
    #pragma unroll
    for (int l = 0; l < 9; ++l) {
        int dy = l/3 - 1, dx = l%3 - 1;
        int yy = tile + dy, xx = rr + dx;
        bool val = (yy >= 0 && yy < IMG && xx >= 0 && xx < IMG);
        lv[l] = val ? (wloc[rr*10 + l] + rpb_lds[l]) : -1e9f;
        mx = fmaxf(mx, lv[l]);
    }

    float s = 0.f;
    #pragma unroll
    for (int t = 0; t < 16; ++t)
        #pragma unroll
        for (int reg = 0; reg < 4; ++reg) {
            float e = __expf(acc[t][reg] - mx);
            acc[t][reg] = e;
            s += e;
        }
    s += __shfl_xor(s, 16, 64);
    s += __shfl_xor(s, 32, 64);
    float sl = 0.f;
    float el[9];
    #pragma unroll
    for (int l = 0; l < 9; ++l) { el[l] = __expf(lv[l] - mx); sl += el[l]; }
    s += sl;
    const float inv = 1.f / s;

    if (lg == 0) {
        #pragma unroll
        for (int l = 0; l < 9; ++l) {
            int dy = l/3 - 1, dx = l%3 - 1;
            int yy = tile + dy, xx = rr + dx;
            bool val = (yy >= 0 && yy < IMG && xx >= 0 && xx < IMG);
            float wl = el[l]*inv + wext[rr*10 + l];
            Wb_lds[((wv*3 + l/3)*16 + la)*40 + (la + 8 + dx)] =
                val ? f2bf(wl) : (ushort_t)0;
        }
    }

    // ---------------- PV ----------------
    f32x4 o0 = {0.f,0.f,0.f,0.f}, o1 = {0.f,0.f,0.f,0.f};

    {   // local: per dy, A=Wb[wv][dy], B=vT window
        const ushort_t* vTh = vT_g + (size_t)(b*NH + hh) * 32 * N_;
        #pragma unroll
        for (int dyi = 0; dyi < 3; ++dyi) {
            int cy = tile + dyi - 1;
            cy = cy < 0 ? 0 : (cy > 63 ? 63 : cy);
            int nb = cy*64 + wv*16 - 8 + lg*8;
            nb = nb < 0 ? 0 : (nb > (N_ - 8) ? (N_ - 8) : nb);
            short8b wf = *(const short8b*)&Wb_lds[((wv*3 + dyi)*16 + la)*40 + lg*8];
            short8b vf0 = *(const short8b*)&vTh[(size_t)la * N_ + nb];
            short8b vf1 = *(const short8b*)&vTh[(size_t)(16 + la) * N_ + nb];
            o0 = __builtin_amdgcn_mfma_f32_16x16x32_bf16(wf, vf0, o0, 0, 0, 0);
            o1 = __builtin_amdgcn_mfma_f32_16x16x32_bf16(wf, vf1, o1, 0, 0, 0);
        }
    }

    {   // pool PV: shuffle-permuted A-frags
        const int src0 = la + 32*(lg & 1);
        const int src1 = src0 + 16;
        const bool hi  = (lg >= 2);
        const ushort_t* vph = vpT_g + ((size_t)(b*NH + hh) * 32) * 256;
        #pragma unroll
        for (int kk = 0; kk < 8; ++kk) {
            unsigned A0 = pk2(acc[2*kk][0]*inv,   acc[2*kk][1]*inv);
            unsigned A1 = pk2(acc[2*kk][2]*inv,   acc[2*kk][3]*inv);
            unsigned B0 = pk2(acc[2*kk+1][0]*inv, acc[2*kk+1][1]*inv);
            unsigned B1 = pk2(acc[2*kk+1][2]*inv, acc[2*kk+1][3]*inv);
            unsigned xa0 = __shfl(A0, src0, 64), xb0 = __shfl(B0, src0, 64);
            unsigned xa1 = __shfl(A1, src0, 64), xb1 = __shfl(B1, src0, 64);
            unsigned ya0 = __shfl(A0, src1, 64), yb0 = __shfl(B0, src1, 64);
            unsigned ya1 = __shfl(A1, src1, 64), yb1 = __shfl(B1, src1, 64);
            union { unsigned u[4]; short8b v; } wf;
            wf.u[0] = hi ? xb0 : xa0;
            wf.u[1] = hi ? xb1 : xa1;
            wf.u[2] = hi ? yb0 : ya0;
            wf.u[3] = hi ? yb1 : ya1;
            short8b vf0 = *(const short8b*)&vph[(size_t)la*256      + kk*32 + lg*8];
            short8b vf1 = *(const short8b*)&vph[(size_t)(16+la)*256 + kk*32 + lg*8];
            o0 = __builtin_amdgcn_mfma_f32_16x16x32_bf16(wf.v, vf0, o0, 0, 0, 0);
            o1 = __builtin_amdgcn_mfma_f32_16x16x32_bf16(wf.v, vf1, o1, 0, 0, 0);
        }
    }

    #pragma unroll
    for (int reg = 0; reg < 4; ++reg) {
        int r2 = r0 + lg*4 + reg;
        int n  = tile*64 + r2;
        ushort_t* orow = outp + ((size_t)(b*N_ + n)) * C_ + hh*32;
        orow[la]      = f2bf(o0[reg]);
        orow[16 + la] = f2bf(o1[reg]);
    }
}

// ---------------------------------------------------------------------------
extern "C" void kernel_launch(void* const* d_in, const int* in_sizes, int n_in,
                              void* d_out, int out_size, void* d_ws, size_t ws_size,
                              hipStream_t stream) {
    const float* x    = (const float*)d_in[0];
    const float* rct  = (const float*)d_in[1];
    const int*   rpi  = (const int*)  d_in[2];
    const float* q_w  = (const float*)d_in[3];
    const float* q_b  = (const float*)d_in[4];
    const float* kv_w = (const float*)d_in[5];
    const float* kv_b = (const float*)d_in[6];
    const float* temp = (const float*)d_in[7];
    const float* qe   = (const float*)d_in[8];
    const float* sr_w = (const float*)d_in[9];
    const float* sr_b = (const float*)d_in[10];
    const float* ng   = (const float*)d_in[11];
    const float* nb   = (const float*)d_in[12];
    const float* c1w  = (const float*)d_in[13];
    const float* c1b  = (const float*)d_in[14];
    const float* c2w  = (const float*)d_in[15];
    const float* c2b  = (const float*)d_in[16];
    const float* rpb  = (const float*)d_in[17];
    const float* lt   = (const float*)d_in[18];
    const float* lb   = (const float*)d_in[19];
    const float* p_w  = (const float*)d_in[20];
    const float* p_b  = (const float*)d_in[21];
    float* out = (float*)d_out;

    float* ws = (float*)d_ws;
    const size_t MN = (size_t)B_ * N_;               // 16384
    float* buf_sr  = ws;                             // [MN,256] f32
    float* buf_t   = buf_sr + MN * 256;              // [8,1024]
    ushort_t* x_bf   = (ushort_t*)(buf_t + 8*1024);  // [MN,256]
    ushort_t* pre_bf = x_bf   + MN * 256;            // [MN,256] attn out
    ushort_t* WTall  = pre_bf + MN * 256;            // [1024,256]
    ushort_t* pwT    = WTall  + 1024*256;            // [256,256]
    ushort_t* qs_bf  = pwT    + 256*256;             // [MN,256]
    ushort_t* knv_bf = qs_bf  + MN * 256;            // [MN,512]
    ushort_t* kp_bf  = knv_bf + MN * 512;            // [B*8*256*32]
    ushort_t* vpT_bf = kp_bf  + (size_t)B_*NH*PL_*32;// [B*8*32*256]
    ushort_t* vT_bf  = vpT_bf + (size_t)B_*NH*32*PL_;// [B*8*32*4096]
    ushort_t* pbl    = vT_bf  + (size_t)B_*NH*32*N_; // [2097152*4]
    ushort_t* xs_bf  = pbl    + (size_t)2097152*4;   // [B*PL,256]

    const int M = (int)MN;  // 16384

    // 1: x convert + weight transposes + CPB MLP
    prep_all<<<2464, 256, 0, stream>>>(x, q_w, kv_w, sr_w, p_w, rct,
                                       c1w, c1b, c2w, c2b, x_bf, WTall, pwT, buf_t);
    // 2: fused q|kv|sr GEMM (+ pb-gather blocks at by>=128) — r12 best config
    gemm_fused<<<dim3(16, 128 + 512), 256, 0, stream>>>(x_bf, WTall, q_b, kv_b, sr_b,
                                                        temp, qe, rpi, buf_t, pbl,
                                                        qs_bf, knv_bf, buf_sr);
    // 3: pool_ln
    mid_prep<<<1024, 256, 0, stream>>>(buf_sr, ng, nb, xs_bf);
    // 4: pooled kv GEMM (+ vtrans blocks overlapped)
    gemm_kvp_vt<<<576, 256, 0, stream>>>(xs_bf, WTall + 256*256, kv_b, knv_bf,
                                         kp_bf, vpT_bf, vT_bf);
    // 5: attention (validated body: 1 tile/block, XCD swizzle)
    attn_v4<<<2048, 256, 0, stream>>>(qs_bf, knv_bf, kp_bf, vpT_bf, vT_bf,
                                      pbl, rpb, qe, temp, lt, lb, pre_bf);
    // 6: output projection
    gemm_mfma<0><<<dim3(4, M/128), 256, 0, stream>>>(pre_bf, pwT, p_b, out, M, 256);
}